// Round 1
// baseline (1353.129 us; speedup 1.0000x reference)
//
#include <hip/hip_runtime.h>
#include <math.h>

#define NB 8
#define NL 2048
#define ND 1024
#define NH 16
#define DHH 64
#define KTOP 7

typedef __attribute__((ext_vector_type(4))) float f32x4;
typedef __attribute__((ext_vector_type(8))) short bf16x8;

__device__ __forceinline__ unsigned short f2bf(float x) {
  unsigned u = __float_as_uint(x);
  u = (u + 0x7FFFu + ((u >> 16) & 1u)) >> 16;
  return (unsigned short)u;
}
__device__ __forceinline__ float bf2f(unsigned short h) {
  return __uint_as_float(((unsigned)h) << 16);
}

// ---------------- weight prep: transpose 1024x1024 and split into bf16 hi/lo ----------------
__global__ __launch_bounds__(256) void wprep_kernel(
    const float* __restrict__ w0, const float* __restrict__ w1,
    const float* __restrict__ w2, const float* __restrict__ w3,
    short* __restrict__ wh, short* __restrict__ wl) {
  __shared__ float tile[32][33];
  const float* in = (blockIdx.y == 0) ? w0 : (blockIdx.y == 1) ? w1
                   : (blockIdx.y == 2) ? w2 : w3;
  short* oh = wh + (size_t)blockIdx.y * ND * ND;
  short* ol = wl + (size_t)blockIdx.y * ND * ND;
  int bx = blockIdx.x & 31, by = blockIdx.x >> 5;
  int tx = threadIdx.x & 31, ty = threadIdx.x >> 5;
#pragma unroll
  for (int i = 0; i < 4; ++i)
    tile[ty + i * 8][tx] = in[(size_t)(by * 32 + ty + i * 8) * ND + bx * 32 + tx];
  __syncthreads();
#pragma unroll
  for (int i = 0; i < 4; ++i) {
    float x = tile[tx][ty + i * 8];
    unsigned short h = f2bf(x);
    unsigned short l = f2bf(x - bf2f(h));
    size_t o = (size_t)(bx * 32 + ty + i * 8) * ND + by * 32 + tx;
    oh[o] = (short)h;
    ol[o] = (short)l;
  }
}

// ---------------- GEMM: A (Mx1024 f32, row-major) x BtT (1024x1024 bf16 hi/lo, N-major) ------
// SPLIT: 3-term split-bf16 (A split on the fly).  TOUT: write C^T as (B,1024,2048).
template <bool SPLIT, bool TOUT>
__global__ __launch_bounds__(256) void gemm_kernel(
    const float* __restrict__ A, const short* __restrict__ BhT,
    const short* __restrict__ BlT, float* __restrict__ C) {
  static_assert(!TOUT || SPLIT, "TOUT epilogue reuses 64KB LDS");
  constexpr int K = 1024, N = 1024;
  __shared__ short smem[SPLIT ? 32768 : 16384];
  short* ah = smem;
  short* bh = smem + 8192;
  constexpr int ALO = SPLIT ? 16384 : 8192;
  constexpr int BLO = SPLIT ? 24576 : 8192;
  short* al = smem + ALO;
  short* bl = smem + BLO;

  int t = threadIdx.x;
  int m0 = (blockIdx.x >> 3) << 7;
  int n0 = (blockIdx.x & 7) << 7;
  int wid = t >> 6, lane = t & 63;
  int wm = wid >> 1, wn = wid & 1;
  int lrow = lane & 15, lk = (lane >> 4) << 3;

  f32x4 acc[4][4] = {};

  for (int k0 = 0; k0 < K; k0 += 64) {
    __syncthreads();
#pragma unroll
    for (int it = 0; it < 8; ++it) {
      int e = it * 256 + t;
      int r = e >> 4, c4 = (e & 15) << 2;
      int widx = (r * 64 + c4) ^ ((r & 7) << 3);
      float4 va = *(const float4*)(A + (size_t)(m0 + r) * K + k0 + c4);
      short4 hb = *(const short4*)(BhT + (size_t)(n0 + r) * K + k0 + c4);
      float vv[4] = {va.x, va.y, va.z, va.w};
      short ha[4], la[4];
#pragma unroll
      for (int j = 0; j < 4; ++j) {
        unsigned short h = f2bf(vv[j]);
        ha[j] = (short)h;
        if (SPLIT) la[j] = (short)f2bf(vv[j] - bf2f(h));
      }
      *(short4*)(ah + widx) = make_short4(ha[0], ha[1], ha[2], ha[3]);
      *(short4*)(bh + widx) = hb;
      if (SPLIT) {
        short4 lb = *(const short4*)(BlT + (size_t)(n0 + r) * K + k0 + c4);
        *(short4*)(al + widx) = make_short4(la[0], la[1], la[2], la[3]);
        *(short4*)(bl + widx) = lb;
      }
    }
    __syncthreads();
#pragma unroll
    for (int kk = 0; kk < 64; kk += 32) {
      bf16x8 afh[4], afl[4];
#pragma unroll
      for (int mf = 0; mf < 4; ++mf) {
        int ar = wm * 64 + mf * 16 + lrow;
        int idx = (ar * 64 + kk + lk) ^ ((ar & 7) << 3);
        afh[mf] = *(const bf16x8*)(ah + idx);
        if (SPLIT) afl[mf] = *(const bf16x8*)(al + idx);
      }
#pragma unroll
      for (int nf = 0; nf < 4; ++nf) {
        int br = wn * 64 + nf * 16 + lrow;
        int idx = (br * 64 + kk + lk) ^ ((br & 7) << 3);
        bf16x8 bfh = *(const bf16x8*)(bh + idx);
#pragma unroll
        for (int mf = 0; mf < 4; ++mf)
          acc[mf][nf] = __builtin_amdgcn_mfma_f32_16x16x32_bf16(afh[mf], bfh, acc[mf][nf], 0, 0, 0);
        if (SPLIT) {
          bf16x8 bfl = *(const bf16x8*)(bl + idx);
#pragma unroll
          for (int mf = 0; mf < 4; ++mf) {
            acc[mf][nf] = __builtin_amdgcn_mfma_f32_16x16x32_bf16(afh[mf], bfl, acc[mf][nf], 0, 0, 0);
            acc[mf][nf] = __builtin_amdgcn_mfma_f32_16x16x32_bf16(afl[mf], bfh, acc[mf][nf], 0, 0, 0);
          }
        }
      }
    }
  }

  if (!TOUT) {
#pragma unroll
    for (int mf = 0; mf < 4; ++mf)
#pragma unroll
      for (int nf = 0; nf < 4; ++nf) {
        int row = m0 + wm * 64 + mf * 16 + (lane >> 4) * 4;
        int col = n0 + wn * 64 + nf * 16 + lrow;
#pragma unroll
        for (int r = 0; r < 4; ++r)
          C[(size_t)(row + r) * N + col] = acc[mf][nf][r];
      }
  } else {
    __syncthreads();
    float* ct = (float*)smem;  // [128][128] f32 == 64KB
#pragma unroll
    for (int mf = 0; mf < 4; ++mf)
#pragma unroll
      for (int nf = 0; nf < 4; ++nf) {
        int nl = wn * 64 + nf * 16 + lrow;
        int ml = wm * 64 + mf * 16 + (lane >> 4) * 4;
#pragma unroll
        for (int r = 0; r < 4; ++r) ct[nl * 128 + ml + r] = acc[mf][nf][r];
      }
    __syncthreads();
    int row = t >> 1, half = t & 1;
    int b = m0 >> 11, mloc = m0 & 2047;
    const float* src = ct + row * 128 + half * 64;
    float* dst = C + (size_t)b * ND * NL + (size_t)(n0 + row) * NL + mloc + half * 64;
#pragma unroll
    for (int j = 0; j < 64; j += 4)
      *(float4*)(dst + j) = *(const float4*)(src + j);
  }
}

// ---------------- FFT correlation + top-7 + softmax, one WG per (b,h,d) lane ----------------
__global__ __launch_bounds__(256) void fft_topk_kernel(
    const float* __restrict__ Qt, const float* __restrict__ Kt,
    float* __restrict__ topw, int* __restrict__ topi) {
  __shared__ float xr[2048], xi[2048], yr[2048], yi[2048];
  __shared__ float twr[1024], twi[1024];
  __shared__ float rv[256];
  __shared__ int ri[256];
  __shared__ float tv[KTOP];

  int t = threadIdx.x;
  size_t rix = blockIdx.x;
  const float* q = Qt + rix * 2048;
  const float* k = Kt + rix * 2048;

  for (int i = t; i < 2048; i += 256) {
    int r = __brev((unsigned)i) >> 21;
    xr[r] = q[i];
    xi[r] = k[i];
  }
  for (int j = t; j < 1024; j += 256) {
    float s, c;
    sincosf(-6.283185307179586f * (float)j / 2048.0f, &s, &c);
    twr[j] = c;
    twi[j] = s;
  }
  __syncthreads();

  // forward FFT (DIT, bit-reversed in, natural out)
  for (int s = 0; s < 11; ++s) {
    int half = 1 << s;
    for (int bb = t; bb < 1024; bb += 256) {
      int grp = bb >> s;
      int j = bb & (half - 1);
      int i0 = (grp << (s + 1)) + j;
      int i1 = i0 + half;
      int ti = j << (10 - s);
      float wr = twr[ti], wi = twi[ti];
      float ar = xr[i1], ai = xi[i1];
      float tr = wr * ar - wi * ai, tm = wr * ai + wi * ar;
      float br = xr[i0], bi = xi[i0];
      xr[i0] = br + tr; xi[i0] = bi + tm;
      xr[i1] = br - tr; xi[i1] = bi - tm;
    }
    __syncthreads();
  }

  // S = FQ * conj(FK), written bit-reversed into y
  for (int f = t; f < 2048; f += 256) {
    int nf = (2048 - f) & 2047;
    float a = xr[f], b2 = xi[f], c = xr[nf], d = xi[nf];
    float p = 0.5f * (a + c), qq = 0.5f * (b2 - d);
    float r2 = 0.5f * (b2 + d), s2 = -0.5f * (a - c);
    float sr = p * r2 + qq * s2;
    float si = qq * r2 - p * s2;
    int rr = __brev((unsigned)f) >> 21;
    yr[rr] = sr;
    yi[rr] = si;
  }
  __syncthreads();

  // inverse FFT (conjugate twiddles)
  for (int s = 0; s < 11; ++s) {
    int half = 1 << s;
    for (int bb = t; bb < 1024; bb += 256) {
      int grp = bb >> s;
      int j = bb & (half - 1);
      int i0 = (grp << (s + 1)) + j;
      int i1 = i0 + half;
      int ti = j << (10 - s);
      float wr = twr[ti], wi = twi[ti];
      float ar = yr[i1], ai = yi[i1];
      float tr = wr * ar + wi * ai, tm = wr * ai - wi * ar;
      float br = yr[i0], bi = yi[i0];
      yr[i0] = br + tr; yi[i0] = bi + tm;
      yr[i1] = br - tr; yi[i1] = bi - tm;
    }
    __syncthreads();
  }

  for (int i = t; i < 2048; i += 256) yr[i] *= (1.0f / 2048.0f);
  __syncthreads();

  // top-7 (lowest index wins ties), then softmax over the 7 values
  for (int pass = 0; pass < KTOP; ++pass) {
    float bv = -3.0e38f;
    int bi2 = 0x7FFFFFFF;
    for (int i = t; i < 2048; i += 256) {
      float v = yr[i];
      if (v > bv) { bv = v; bi2 = i; }
    }
    rv[t] = bv;
    ri[t] = bi2;
    __syncthreads();
    for (int s = 128; s > 0; s >>= 1) {
      if (t < s) {
        float ov = rv[t + s];
        int oi = ri[t + s];
        if (ov > rv[t] || (ov == rv[t] && oi < ri[t])) { rv[t] = ov; ri[t] = oi; }
      }
      __syncthreads();
    }
    if (t == 0) {
      tv[pass] = rv[0];
      topi[rix * KTOP + pass] = ri[0];
      yr[ri[0]] = -3.0e38f;
    }
    __syncthreads();
  }
  if (t == 0) {
    float m = tv[0], ssum = 0.f, w[KTOP];
#pragma unroll
    for (int i = 0; i < KTOP; ++i) { w[i] = expf(tv[i] - m); ssum += w[i]; }
#pragma unroll
    for (int i = 0; i < KTOP; ++i) topw[rix * KTOP + i] = w[i] / ssum;
  }
}

// ---------------- roll (mod-64 over Dh) + weight + scramble-layout write --------------------
__global__ __launch_bounds__(256) void roll_kernel(
    const float* __restrict__ V, const float* __restrict__ topw,
    const int* __restrict__ topi, float* __restrict__ out) {
  __shared__ float vt[64][65];
  __shared__ float ws[64][8];
  __shared__ int ts[64][8];
  int blk = blockIdx.x;
  int b = blk >> 9;
  int h = (blk >> 5) & 15;
  int lc = blk & 31;
  int t = threadIdx.x;

#pragma unroll
  for (int it = 0; it < 16; ++it) {
    int e = it * 256 + t;
    int r = e >> 6, d = e & 63;
    vt[d][r] = V[((size_t)(b * 2048 + lc * 64 + r)) * ND + h * 64 + d];
  }
  for (int e = t; e < 64 * KTOP; e += 256) {
    int d = e / KTOP, i = e % KTOP;
    size_t rix = ((size_t)(b * 16 + h)) * 64 + d;
    ws[d][i] = topw[rix * KTOP + i];
    ts[d][i] = topi[rix * KTOP + i] & 63;
  }
  __syncthreads();

  int hi = lc >> 4;
  int c0 = (lc & 15) * 64;
#pragma unroll
  for (int it = 0; it < 16; ++it) {
    int e = it * 256 + t;
    int d = e >> 6, r = e & 63;
    float s = 0.f;
#pragma unroll
    for (int i = 0; i < KTOP; ++i) s += ws[d][i] * vt[(d - ts[d][i]) & 63][r];
    int rowp = d * 32 + h * 2 + hi;
    out[((size_t)(b * 2048 + rowp)) * ND + c0 + r] = s;
  }
}

// ------------------------------------- launcher ---------------------------------------------
extern "C" void kernel_launch(void* const* d_in, const int* in_sizes, int n_in,
                              void* d_out, int out_size, void* d_ws, size_t ws_size,
                              hipStream_t stream) {
  (void)in_sizes; (void)n_in; (void)out_size; (void)ws_size;
  const float* queries = (const float*)d_in[0];
  const float* keys    = (const float*)d_in[1];
  const float* values  = (const float*)d_in[2];
  const float* wq = (const float*)d_in[3];
  const float* wk = (const float*)d_in[4];
  const float* wv = (const float*)d_in[5];
  const float* wo = (const float*)d_in[6];
  float* outp = (float*)d_out;

  // workspace layout
  short* wh = (short*)d_ws;                       // 4 x 1024x1024 bf16 hi (8MB)
  short* wl = wh + (size_t)4 * ND * ND;           // 4 x 1024x1024 bf16 lo (8MB)
  float* bufA = (float*)(wl + (size_t)4 * ND * ND);      // 64MB: Qt, later scrambled
  float* bufB = bufA + (size_t)NB * ND * NL;             // 64MB: Kt, later Vproj
  float* topw = bufB + (size_t)NB * ND * NL;             // 8192*7 f32
  int* topi = (int*)(topw + (size_t)8192 * KTOP);        // 8192*7 i32

  short* wqh = wh + (size_t)0 * ND * ND; short* wql = wl + (size_t)0 * ND * ND;
  short* wkh = wh + (size_t)1 * ND * ND; short* wkl = wl + (size_t)1 * ND * ND;
  short* wvh = wh + (size_t)2 * ND * ND;
  short* woh = wh + (size_t)3 * ND * ND;

  wprep_kernel<<<dim3(1024, 4), 256, 0, stream>>>(wq, wk, wv, wo, wh, wl);

  // Q^T, K^T : (B,1024,2048), split-precision
  gemm_kernel<true, true><<<dim3(1024), 256, 0, stream>>>(queries, wqh, wql, bufA);
  gemm_kernel<true, true><<<dim3(1024), 256, 0, stream>>>(keys, wkh, wkl, bufB);

  // corr -> top7 -> softmax
  fft_topk_kernel<<<dim3(8192), 256, 0, stream>>>(bufA, bufB, topw, topi);

  // V (natural layout), plain bf16 — reuses Kt buffer
  gemm_kernel<false, false><<<dim3(1024), 256, 0, stream>>>(values, wvh, nullptr, bufB);

  // roll + scramble — reuses Qt buffer
  roll_kernel<<<dim3(NB * NH * 32), 256, 0, stream>>>(bufB, topw, topi, bufA);

  // final projection
  gemm_kernel<false, false><<<dim3(1024), 256, 0, stream>>>(bufA, woh, nullptr, outp);
}

// Round 2
// 997.053 us; speedup vs baseline: 1.3571x; 1.3571x over previous
//
#include <hip/hip_runtime.h>
#include <math.h>

#define NB 8
#define NL 2048
#define ND 1024
#define NH 16
#define DHH 64
#define KTOP 7

typedef __attribute__((ext_vector_type(4))) float f32x4;
typedef __attribute__((ext_vector_type(8))) short bf16x8;

__device__ __forceinline__ unsigned short f2bf(float x) {
  unsigned u = __float_as_uint(x);
  u = (u + 0x7FFFu + ((u >> 16) & 1u)) >> 16;
  return (unsigned short)u;
}
__device__ __forceinline__ float bf2f(unsigned short h) {
  return __uint_as_float(((unsigned)h) << 16);
}

// ---------------- weight prep: transpose 1024x1024 and split into bf16 hi/lo ----------------
__global__ __launch_bounds__(256) void wprep_kernel(
    const float* __restrict__ w0, const float* __restrict__ w1,
    const float* __restrict__ w2, const float* __restrict__ w3,
    short* __restrict__ wh, short* __restrict__ wl) {
  __shared__ float tile[32][33];
  const float* in = (blockIdx.y == 0) ? w0 : (blockIdx.y == 1) ? w1
                   : (blockIdx.y == 2) ? w2 : w3;
  short* oh = wh + (size_t)blockIdx.y * ND * ND;
  short* ol = wl + (size_t)blockIdx.y * ND * ND;
  int bx = blockIdx.x & 31, by = blockIdx.x >> 5;
  int tx = threadIdx.x & 31, ty = threadIdx.x >> 5;
#pragma unroll
  for (int i = 0; i < 4; ++i)
    tile[ty + i * 8][tx] = in[(size_t)(by * 32 + ty + i * 8) * ND + bx * 32 + tx];
  __syncthreads();
#pragma unroll
  for (int i = 0; i < 4; ++i) {
    float x = tile[tx][ty + i * 8];
    unsigned short h = f2bf(x);
    unsigned short l = f2bf(x - bf2f(h));
    size_t o = (size_t)(bx * 32 + ty + i * 8) * ND + by * 32 + tx;
    oh[o] = (short)h;
    ol[o] = (short)l;
  }
}

// ---------------- GEMM: A (Mx1024 f32, row-major) x BtT (1024x1024 bf16 hi/lo, N-major) ------
// SPLIT: 3-term split-bf16 (A split on the fly).  TOUT: write C^T as (B,1024,2048).
template <bool SPLIT, bool TOUT>
__global__ __launch_bounds__(256) void gemm_kernel(
    const float* __restrict__ A, const short* __restrict__ BhT,
    const short* __restrict__ BlT, float* __restrict__ C) {
  static_assert(!TOUT || SPLIT, "TOUT epilogue reuses 64KB LDS");
  constexpr int K = 1024, N = 1024;
  __shared__ short smem[SPLIT ? 32768 : 16384];
  short* ah = smem;
  short* bh = smem + 8192;
  constexpr int ALO = SPLIT ? 16384 : 8192;
  constexpr int BLO = SPLIT ? 24576 : 8192;
  short* al = smem + ALO;
  short* bl = smem + BLO;

  int t = threadIdx.x;
  int m0 = (blockIdx.x >> 3) << 7;
  int n0 = (blockIdx.x & 7) << 7;
  int wid = t >> 6, lane = t & 63;
  int wm = wid >> 1, wn = wid & 1;
  int lrow = lane & 15, lk = (lane >> 4) << 3;

  f32x4 acc[4][4] = {};

  for (int k0 = 0; k0 < K; k0 += 64) {
    __syncthreads();
#pragma unroll
    for (int it = 0; it < 8; ++it) {
      int e = it * 256 + t;
      int r = e >> 4, c4 = (e & 15) << 2;
      int widx = (r * 64 + c4) ^ ((r & 7) << 3);
      float4 va = *(const float4*)(A + (size_t)(m0 + r) * K + k0 + c4);
      short4 hb = *(const short4*)(BhT + (size_t)(n0 + r) * K + k0 + c4);
      float vv[4] = {va.x, va.y, va.z, va.w};
      short ha[4], la[4];
#pragma unroll
      for (int j = 0; j < 4; ++j) {
        unsigned short h = f2bf(vv[j]);
        ha[j] = (short)h;
        if (SPLIT) la[j] = (short)f2bf(vv[j] - bf2f(h));
      }
      *(short4*)(ah + widx) = make_short4(ha[0], ha[1], ha[2], ha[3]);
      *(short4*)(bh + widx) = hb;
      if (SPLIT) {
        short4 lb = *(const short4*)(BlT + (size_t)(n0 + r) * K + k0 + c4);
        *(short4*)(al + widx) = make_short4(la[0], la[1], la[2], la[3]);
        *(short4*)(bl + widx) = lb;
      }
    }
    __syncthreads();
#pragma unroll
    for (int kk = 0; kk < 64; kk += 32) {
      bf16x8 afh[4], afl[4];
#pragma unroll
      for (int mf = 0; mf < 4; ++mf) {
        int ar = wm * 64 + mf * 16 + lrow;
        int idx = (ar * 64 + kk + lk) ^ ((ar & 7) << 3);
        afh[mf] = *(const bf16x8*)(ah + idx);
        if (SPLIT) afl[mf] = *(const bf16x8*)(al + idx);
      }
#pragma unroll
      for (int nf = 0; nf < 4; ++nf) {
        int br = wn * 64 + nf * 16 + lrow;
        int idx = (br * 64 + kk + lk) ^ ((br & 7) << 3);
        bf16x8 bfh = *(const bf16x8*)(bh + idx);
#pragma unroll
        for (int mf = 0; mf < 4; ++mf)
          acc[mf][nf] = __builtin_amdgcn_mfma_f32_16x16x32_bf16(afh[mf], bfh, acc[mf][nf], 0, 0, 0);
        if (SPLIT) {
          bf16x8 bfl = *(const bf16x8*)(bl + idx);
#pragma unroll
          for (int mf = 0; mf < 4; ++mf) {
            acc[mf][nf] = __builtin_amdgcn_mfma_f32_16x16x32_bf16(afh[mf], bfl, acc[mf][nf], 0, 0, 0);
            acc[mf][nf] = __builtin_amdgcn_mfma_f32_16x16x32_bf16(afl[mf], bfh, acc[mf][nf], 0, 0, 0);
          }
        }
      }
    }
  }

  if (!TOUT) {
#pragma unroll
    for (int mf = 0; mf < 4; ++mf)
#pragma unroll
      for (int nf = 0; nf < 4; ++nf) {
        int row = m0 + wm * 64 + mf * 16 + (lane >> 4) * 4;
        int col = n0 + wn * 64 + nf * 16 + lrow;
#pragma unroll
        for (int r = 0; r < 4; ++r)
          C[(size_t)(row + r) * N + col] = acc[mf][nf][r];
      }
  } else {
    __syncthreads();
    float* ct = (float*)smem;  // [128][128] f32 == 64KB
#pragma unroll
    for (int mf = 0; mf < 4; ++mf)
#pragma unroll
      for (int nf = 0; nf < 4; ++nf) {
        int nl = wn * 64 + nf * 16 + lrow;
        int ml = wm * 64 + mf * 16 + (lane >> 4) * 4;
#pragma unroll
        for (int r = 0; r < 4; ++r) ct[nl * 128 + ml + r] = acc[mf][nf][r];
      }
    __syncthreads();
    int row = t >> 1, half = t & 1;
    int b = m0 >> 11, mloc = m0 & 2047;
    const float* src = ct + row * 128 + half * 64;
    float* dst = C + (size_t)b * ND * NL + (size_t)(n0 + row) * NL + mloc + half * 64;
#pragma unroll
    for (int j = 0; j < 64; j += 4)
      *(float4*)(dst + j) = *(const float4*)(src + j);
  }
}

// =================== FFT correlation + top-7 + softmax (register Stockham) ===================
__device__ __forceinline__ int SW(int i) { return i ^ ((i >> 4) & 7); }

__device__ __forceinline__ float2 cadd2(float2 a, float2 b) { return make_float2(a.x + b.x, a.y + b.y); }
__device__ __forceinline__ float2 csub2(float2 a, float2 b) { return make_float2(a.x - b.x, a.y - b.y); }
__device__ __forceinline__ float2 cmul2(float2 a, float2 b) {
  return make_float2(a.x * b.x - a.y * b.y, a.x * b.y + a.y * b.x);
}
// multiply by (s*i)
__device__ __forceinline__ float2 cjs2(float2 a, float s) { return make_float2(-s * a.y, s * a.x); }

__device__ __forceinline__ void dft4(float2& b0, float2& b1, float2& b2, float2& b3, float s) {
  float2 t0 = cadd2(b0, b2), t1 = csub2(b0, b2);
  float2 t2 = cadd2(b1, b3), t3 = cjs2(csub2(b1, b3), s);
  b0 = cadd2(t0, t2);
  b1 = cadd2(t1, t3);
  b2 = csub2(t0, t2);
  b3 = csub2(t1, t3);
}

__device__ __forceinline__ void dft8(float2 a[8], float s) {
  float2 e0 = a[0], e1 = a[2], e2 = a[4], e3 = a[6];
  float2 o0 = a[1], o1 = a[3], o2 = a[5], o3 = a[7];
  dft4(e0, e1, e2, e3, s);
  dft4(o0, o1, o2, o3, s);
  const float c = 0.70710678118654752f;
  float2 w1 = make_float2(c, s * c);
  float2 w3 = make_float2(-c, s * c);
  o1 = cmul2(o1, w1);
  o2 = cjs2(o2, s);
  o3 = cmul2(o3, w3);
  a[0] = cadd2(e0, o0);
  a[4] = csub2(e0, o0);
  a[1] = cadd2(e1, o1);
  a[5] = csub2(e1, o1);
  a[2] = cadd2(e2, o2);
  a[6] = csub2(e2, o2);
  a[3] = cadd2(e3, o3);
  a[7] = csub2(e3, o3);
}

// one radix-8 Stockham pass, one butterfly per thread (Ns = 256)
template <int LS>
__device__ __forceinline__ void pass8(const float2* __restrict__ in, float2* __restrict__ out,
                                      float s, int t) {
  int k = t & (LS - 1);
  int blk = t / LS;
  float2 a[8];
#pragma unroll
  for (int r = 0; r < 8; ++r) a[r] = in[SW(t + 256 * r)];
  if (LS > 1) {
    float ang = s * (6.283185307179586f / (float)(LS * 8)) * (float)k;
    float2 w;
    sincosf(ang, &w.y, &w.x);
    float2 wr = w;
    a[1] = cmul2(a[1], wr);
#pragma unroll
    for (int r = 2; r < 8; ++r) {
      wr = cmul2(wr, w);
      a[r] = cmul2(a[r], wr);
    }
  }
  dft8(a, s);
  int ob = blk * (LS * 8) + k;
#pragma unroll
  for (int r = 0; r < 8; ++r) out[SW(ob + LS * r)] = a[r];
}

__global__ __launch_bounds__(256) void fft_topk_kernel(
    const float* __restrict__ Qt, const float* __restrict__ Kt,
    float* __restrict__ topw, int* __restrict__ topi) {
  __shared__ float2 X[2048];
  __shared__ float2 Y[2048];
  __shared__ float cv[4];
  __shared__ int ct[4];

  int t = threadIdx.x;
  size_t rix = blockIdx.x;
  const float* q = Qt + rix * 2048;
  const float* k = Kt + rix * 2048;

  // load packed z = Q + i*K (natural order, swizzled LDS)
#pragma unroll
  for (int it = 0; it < 2; ++it) {
    int i0 = 4 * t + 1024 * it;
    float4 vq = *(const float4*)(q + i0);
    float4 vk = *(const float4*)(k + i0);
    X[SW(i0 + 0)] = make_float2(vq.x, vk.x);
    X[SW(i0 + 1)] = make_float2(vq.y, vk.y);
    X[SW(i0 + 2)] = make_float2(vq.z, vk.z);
    X[SW(i0 + 3)] = make_float2(vq.w, vk.w);
  }
  __syncthreads();

  // forward FFT (sign = -1): radix 8,8,8,4
  pass8<1>(X, Y, -1.0f, t);
  __syncthreads();
  pass8<8>(Y, X, -1.0f, t);
  __syncthreads();
  pass8<64>(X, Y, -1.0f, t);
  __syncthreads();
  // pass 3: R=4, Ls=512, two butterflies/thread, Y -> X
#pragma unroll
  for (int h = 0; h < 2; ++h) {
    int b = t + 256 * h;
    float2 a[4];
#pragma unroll
    for (int r = 0; r < 4; ++r) a[r] = Y[SW(b + 512 * r)];
    float ang = -(6.283185307179586f / 2048.0f) * (float)b;
    float2 w;
    sincosf(ang, &w.y, &w.x);
    a[1] = cmul2(a[1], w);
    float2 w2 = cmul2(w, w);
    a[2] = cmul2(a[2], w2);
    a[3] = cmul2(a[3], cmul2(w2, w));
    dft4(a[0], a[1], a[2], a[3], -1.0f);
#pragma unroll
    for (int r = 0; r < 4; ++r) X[SW(b + 512 * r)] = a[r];
  }
  __syncthreads();

  // spectrum untangle: S = FQ * conj(FK), scaled by 1/2048; X -> Y
#pragma unroll
  for (int it = 0; it < 8; ++it) {
    int f = t + 256 * it;
    int nf = (2048 - f) & 2047;
    float2 zf = X[SW(f)];
    float2 zn = X[SW(nf)];
    float a = zf.x, b2 = zf.y, c = zn.x, d = zn.y;
    float p = 0.5f * (a + c), qq = 0.5f * (b2 - d);
    float r2 = 0.5f * (b2 + d), s2 = -0.5f * (a - c);
    Y[SW(f)] = make_float2((p * r2 + qq * s2) * (1.0f / 2048.0f),
                           (qq * r2 - p * s2) * (1.0f / 2048.0f));
  }
  __syncthreads();

  // inverse FFT (sign = +1): radix 8,8,8 then final radix-4 kept in registers
  pass8<1>(Y, X, 1.0f, t);
  __syncthreads();
  pass8<8>(X, Y, 1.0f, t);
  __syncthreads();
  pass8<64>(Y, X, 1.0f, t);
  __syncthreads();

  float lv[8];
  int lt[8];
#pragma unroll
  for (int h = 0; h < 2; ++h) {
    int b = t + 256 * h;
    float2 a[4];
#pragma unroll
    for (int r = 0; r < 4; ++r) a[r] = X[SW(b + 512 * r)];
    float ang = (6.283185307179586f / 2048.0f) * (float)b;
    float2 w;
    sincosf(ang, &w.y, &w.x);
    a[1] = cmul2(a[1], w);
    float2 w2 = cmul2(w, w);
    a[2] = cmul2(a[2], w2);
    a[3] = cmul2(a[3], cmul2(w2, w));
    dft4(a[0], a[1], a[2], a[3], 1.0f);
#pragma unroll
    for (int r = 0; r < 4; ++r) {
      lv[h * 4 + r] = a[r].x;  // corr is real
      lt[h * 4 + r] = b + 512 * r;
    }
  }

  // top-7 across 2048 register-held values (lowest tau wins ties)
  int lane = t & 63, wave = t >> 6;
  float sel_v[KTOP];
  int sel_t[KTOP];
#pragma unroll
  for (int pass = 0; pass < KTOP; ++pass) {
    float bv = -3.0e38f;
    int bt = 0x7FFFFFFF;
#pragma unroll
    for (int j = 0; j < 8; ++j)
      if (lv[j] > bv || (lv[j] == bv && lt[j] < bt)) { bv = lv[j]; bt = lt[j]; }
#pragma unroll
    for (int m = 1; m < 64; m <<= 1) {
      float ov = __shfl_xor(bv, m, 64);
      int ot = __shfl_xor(bt, m, 64);
      if (ov > bv || (ov == bv && ot < bt)) { bv = ov; bt = ot; }
    }
    if (lane == 0) { cv[wave] = bv; ct[wave] = bt; }
    __syncthreads();
    float fv = cv[0];
    int ft = ct[0];
#pragma unroll
    for (int w = 1; w < 4; ++w) {
      float ov = cv[w];
      int ot = ct[w];
      if (ov > fv || (ov == fv && ot < ft)) { fv = ov; ft = ot; }
    }
    sel_v[pass] = fv;
    sel_t[pass] = ft;
#pragma unroll
    for (int j = 0; j < 8; ++j)
      if (lt[j] == ft) lv[j] = -3.0e38f;
    __syncthreads();
  }

  if (t == 0) {
    float m = sel_v[0], ssum = 0.f, w[KTOP];
#pragma unroll
    for (int i = 0; i < KTOP; ++i) { w[i] = expf(sel_v[i] - m); ssum += w[i]; }
#pragma unroll
    for (int i = 0; i < KTOP; ++i) {
      topw[rix * KTOP + i] = w[i] / ssum;
      topi[rix * KTOP + i] = sel_t[i];
    }
  }
}

// ---------------- roll (mod-64 over Dh) + weight + scramble-layout write --------------------
__global__ __launch_bounds__(256) void roll_kernel(
    const float* __restrict__ V, const float* __restrict__ topw,
    const int* __restrict__ topi, float* __restrict__ out) {
  __shared__ float vt[64][65];
  __shared__ float ws[64][8];
  __shared__ int ts[64][8];
  int blk = blockIdx.x;
  int b = blk >> 9;
  int h = (blk >> 5) & 15;
  int lc = blk & 31;
  int t = threadIdx.x;

#pragma unroll
  for (int it = 0; it < 16; ++it) {
    int e = it * 256 + t;
    int r = e >> 6, d = e & 63;
    vt[d][r] = V[((size_t)(b * 2048 + lc * 64 + r)) * ND + h * 64 + d];
  }
  for (int e = t; e < 64 * KTOP; e += 256) {
    int d = e / KTOP, i = e % KTOP;
    size_t rix = ((size_t)(b * 16 + h)) * 64 + d;
    ws[d][i] = topw[rix * KTOP + i];
    ts[d][i] = topi[rix * KTOP + i] & 63;
  }
  __syncthreads();

  int hi = lc >> 4;
  int c0 = (lc & 15) * 64;
#pragma unroll
  for (int it = 0; it < 16; ++it) {
    int e = it * 256 + t;
    int d = e >> 6, r = e & 63;
    float s = 0.f;
#pragma unroll
    for (int i = 0; i < KTOP; ++i) s += ws[d][i] * vt[(d - ts[d][i]) & 63][r];
    int rowp = d * 32 + h * 2 + hi;
    out[((size_t)(b * 2048 + rowp)) * ND + c0 + r] = s;
  }
}

// ------------------------------------- launcher ---------------------------------------------
extern "C" void kernel_launch(void* const* d_in, const int* in_sizes, int n_in,
                              void* d_out, int out_size, void* d_ws, size_t ws_size,
                              hipStream_t stream) {
  (void)in_sizes; (void)n_in; (void)out_size; (void)ws_size;
  const float* queries = (const float*)d_in[0];
  const float* keys    = (const float*)d_in[1];
  const float* values  = (const float*)d_in[2];
  const float* wq = (const float*)d_in[3];
  const float* wk = (const float*)d_in[4];
  const float* wv = (const float*)d_in[5];
  const float* wo = (const float*)d_in[6];
  float* outp = (float*)d_out;

  // workspace layout
  short* wh = (short*)d_ws;                       // 4 x 1024x1024 bf16 hi (8MB)
  short* wl = wh + (size_t)4 * ND * ND;           // 4 x 1024x1024 bf16 lo (8MB)
  float* bufA = (float*)(wl + (size_t)4 * ND * ND);      // 64MB: Qt, later scrambled
  float* bufB = bufA + (size_t)NB * ND * NL;             // 64MB: Kt, later Vproj
  float* topw = bufB + (size_t)NB * ND * NL;             // 8192*7 f32
  int* topi = (int*)(topw + (size_t)8192 * KTOP);        // 8192*7 i32

  short* wqh = wh + (size_t)0 * ND * ND; short* wql = wl + (size_t)0 * ND * ND;
  short* wkh = wh + (size_t)1 * ND * ND; short* wkl = wl + (size_t)1 * ND * ND;
  short* wvh = wh + (size_t)2 * ND * ND;
  short* woh = wh + (size_t)3 * ND * ND;

  wprep_kernel<<<dim3(1024, 4), 256, 0, stream>>>(wq, wk, wv, wo, wh, wl);

  // Q^T, K^T : (B,1024,2048), split-precision
  gemm_kernel<true, true><<<dim3(1024), 256, 0, stream>>>(queries, wqh, wql, bufA);
  gemm_kernel<true, true><<<dim3(1024), 256, 0, stream>>>(keys, wkh, wkl, bufB);

  // corr -> top7 -> softmax
  fft_topk_kernel<<<dim3(8192), 256, 0, stream>>>(bufA, bufB, topw, topi);

  // V (natural layout), plain bf16 — reuses Kt buffer
  gemm_kernel<false, false><<<dim3(1024), 256, 0, stream>>>(values, wvh, nullptr, bufB);

  // roll + scramble — reuses Qt buffer
  roll_kernel<<<dim3(NB * NH * 32), 256, 0, stream>>>(bufB, topw, topi, bufA);

  // final projection
  gemm_kernel<false, false><<<dim3(1024), 256, 0, stream>>>(bufA, woh, nullptr, outp);
}

// Round 4
// 545.010 us; speedup vs baseline: 2.4828x; 1.8294x over previous
//
#include <hip/hip_runtime.h>
#include <math.h>

#define NB 8
#define NL 2048
#define ND 1024
#define NH 16
#define KTOP 7

typedef __attribute__((ext_vector_type(4))) float f32x4;
typedef __attribute__((ext_vector_type(8))) short s16x8;
typedef __attribute__((ext_vector_type(8))) _Float16 f16x8;
typedef __attribute__((ext_vector_type(4))) _Float16 f16x4;

__device__ __forceinline__ unsigned short f2bf(float x) {
  unsigned u = __float_as_uint(x);
  u = (u + 0x7FFFu + ((u >> 16) & 1u)) >> 16;
  return (unsigned short)u;
}
__device__ __forceinline__ float bf2f(unsigned short h) {
  return __uint_as_float(((unsigned)h) << 16);
}
__device__ __forceinline__ void gll16(const void* g, void* l) {
  __builtin_amdgcn_global_load_lds(
      (const __attribute__((address_space(1))) void*)g,
      (__attribute__((address_space(3))) void*)l, 16, 0, 0);
}

// ---------------- weight prep ----------------
// y=0,1 (wq,wk): transpose -> split bf16 hi/lo, swizzled for BK=32 tiles (k ^ ((n&3)<<3))
// y=2,3 (wv,wo): transpose -> f16, swizzled for BK=64 tiles (k ^ ((n&7)<<3))
__global__ __launch_bounds__(256) void wprep_kernel(
    const float* __restrict__ w0, const float* __restrict__ w1,
    const float* __restrict__ w2, const float* __restrict__ w3,
    short* __restrict__ wsplit,   // [wqh|wql|wkh|wkl] each 1M shorts
    _Float16* __restrict__ wf16)  // [wv|wo] each 1M halfs
{
  __shared__ float tile[32][33];
  int y = blockIdx.y;
  const float* in = (y == 0) ? w0 : (y == 1) ? w1 : (y == 2) ? w2 : w3;
  int bx = blockIdx.x & 31, by = blockIdx.x >> 5;
  int tx = threadIdx.x & 31, ty = threadIdx.x >> 5;
#pragma unroll
  for (int i = 0; i < 4; ++i)
    tile[ty + i * 8][tx] = in[(size_t)(by * 32 + ty + i * 8) * ND + bx * 32 + tx];
  __syncthreads();
#pragma unroll
  for (int i = 0; i < 4; ++i) {
    float x = tile[tx][ty + i * 8];
    int n = bx * 32 + ty + i * 8;
    int k = by * 32 + tx;
    if (y < 2) {
      short* oh = wsplit + (size_t)(2 * y) * ND * ND;
      short* ol = wsplit + (size_t)(2 * y + 1) * ND * ND;
      unsigned short h = f2bf(x);
      unsigned short l = f2bf(x - bf2f(h));
      size_t o = (size_t)n * ND + (k ^ ((n & 3) << 3));
      oh[o] = (short)h;
      ol[o] = (short)l;
    } else {
      _Float16* of = wf16 + (size_t)(y - 2) * ND * ND;
      of[(size_t)n * ND + (k ^ ((n & 7) << 3))] = (_Float16)x;
    }
  }
}

// ---------------- split-bf16 GEMM: C^T = (A f32 x BT split-bf16), out (B,1024,2048) f32 -----
__global__ __launch_bounds__(256) void gemm_split(
    const float* __restrict__ A, const short* __restrict__ BhT,
    const short* __restrict__ BlT, float* __restrict__ Ct) {
  constexpr int K = 1024;
  __shared__ short ah[4096], al[4096], bh[4096], bl[4096];  // 32KB, BK=32
  int t = threadIdx.x;
  int wg = (blockIdx.x & 7) * 128 + (blockIdx.x >> 3);  // bijective XCD swizzle
  int m0 = (wg >> 3) << 7, n0 = (wg & 7) << 7;
  int lane = t & 63;
  int wm = (t >> 7) & 1, wn = (t >> 6) & 1;
  int lrow = lane & 15, lk8 = (lane >> 4) << 3;

  f32x4 acc[4][4] = {};

  for (int k0 = 0; k0 < K; k0 += 32) {
    // B hi/lo: async direct-to-LDS (source pre-split + pre-swizzled)
#pragma unroll
    for (int it = 0; it < 2; ++it) {
      int cb = it * 256 + t;
      int r = cb >> 2, c8 = (cb & 3) << 3;
      int lo = it * 2048 + (t & 192) * 8;  // wave-uniform (halfs)
      gll16(BhT + (size_t)(n0 + r) * K + k0 + c8, bh + lo);
      gll16(BlT + (size_t)(n0 + r) * K + k0 + c8, bl + lo);
    }
    // A: load f32, split to bf16 hi/lo, swizzled LDS write
#pragma unroll
    for (int it = 0; it < 2; ++it) {
      int ca = it * 256 + t;
      int r = ca >> 2, c8 = (ca & 3) << 3;
      const float* pa = A + (size_t)(m0 + r) * K + k0 + c8;
      float4 x = *(const float4*)pa;
      float4 y = *(const float4*)(pa + 4);
      float v[8] = {x.x, x.y, x.z, x.w, y.x, y.y, y.z, y.w};
      s16x8 hv, lv;
#pragma unroll
      for (int j = 0; j < 8; ++j) {
        unsigned short h = f2bf(v[j]);
        hv[j] = (short)h;
        lv[j] = (short)(unsigned short)(__float_as_uint(v[j] - bf2f(h)) >> 16);
      }
      int wi = r * 32 + (c8 ^ ((r & 3) << 3));
      *(s16x8*)(ah + wi) = hv;
      *(s16x8*)(al + wi) = lv;
    }
    __syncthreads();

    s16x8 afh[4], afl[4];
#pragma unroll
    for (int mf = 0; mf < 4; ++mf) {
      int row = wm * 64 + mf * 16 + lrow;
      int idx = row * 32 + (lk8 ^ ((row & 3) << 3));
      afh[mf] = *(const s16x8*)(ah + idx);
      afl[mf] = *(const s16x8*)(al + idx);
    }
#pragma unroll
    for (int nf = 0; nf < 4; ++nf) {
      int row = wn * 64 + nf * 16 + lrow;
      int idx = row * 32 + (lk8 ^ ((row & 3) << 3));
      s16x8 bfh = *(const s16x8*)(bh + idx);
      s16x8 bfl = *(const s16x8*)(bl + idx);
#pragma unroll
      for (int mf = 0; mf < 4; ++mf) {
        acc[mf][nf] = __builtin_amdgcn_mfma_f32_16x16x32_bf16(afh[mf], bfh, acc[mf][nf], 0, 0, 0);
        acc[mf][nf] = __builtin_amdgcn_mfma_f32_16x16x32_bf16(afh[mf], bfl, acc[mf][nf], 0, 0, 0);
        acc[mf][nf] = __builtin_amdgcn_mfma_f32_16x16x32_bf16(afl[mf], bfh, acc[mf][nf], 0, 0, 0);
      }
    }
    __syncthreads();
  }

  // epilogue: C^T (B,1024,2048) f32, float4 stores along m
  int b = m0 >> 11;
  int mlbase = (m0 & 2047) + wm * 64 + (lane >> 4) * 4;
#pragma unroll
  for (int nf = 0; nf < 4; ++nf) {
    int n = n0 + wn * 64 + nf * 16 + lrow;
    float* rowp = Ct + ((size_t)(b * ND + n)) * NL + mlbase;
#pragma unroll
    for (int mf = 0; mf < 4; ++mf)
      *(float4*)(rowp + mf * 16) = *(float4*)&acc[mf][nf];
  }
}

// ---------------- f16 GEMM: A x BT(f16 pre-swizzled, gll) --------------------------------
// AF32: A is f32 natural (VALU-staged, cast f16); else A is f16 pre-swizzled (gll).
// OUTMODE 0: C^T (B,1024,2048) f16.  OUTMODE 2: C natural (16384x1024) f32.
template <int OUTMODE, bool AF32>
__global__ __launch_bounds__(256) void gemm_f16(
    const void* __restrict__ Av, const _Float16* __restrict__ BT,
    void* __restrict__ Cv) {
  constexpr int K = 1024;
  __shared__ _Float16 sA[8192];  // 128 x 64, swizzled
  __shared__ _Float16 sB[8192];
  int t = threadIdx.x;
  int wg = (blockIdx.x & 7) * 128 + (blockIdx.x >> 3);
  int m0 = (wg >> 3) << 7, n0 = (wg & 7) << 7;
  int lane = t & 63;
  int wm = (t >> 7) & 1, wn = (t >> 6) & 1;
  int lrow = lane & 15, lk = (lane >> 4) << 3;

  f32x4 acc[4][4] = {};

  for (int k0 = 0; k0 < K; k0 += 64) {
    // B: gll (pre-swizzled source)
#pragma unroll
    for (int it = 0; it < 4; ++it) {
      int e = it * 256 + t;
      int r = e >> 3, c8 = (e & 7) << 3;
      int lo = it * 2048 + (t & 192) * 8;
      gll16(BT + (size_t)(n0 + r) * K + k0 + c8, sB + lo);
      if (!AF32) {
        const _Float16* Af = (const _Float16*)Av;
        gll16(Af + (size_t)(m0 + r) * K + k0 + c8, sA + lo);
      }
    }
    if (AF32) {
      const float* Af = (const float*)Av;
#pragma unroll
      for (int it = 0; it < 4; ++it) {
        int ca = it * 256 + t;
        int r = ca >> 3, c8 = (ca & 7) << 3;
        const float* pa = Af + (size_t)(m0 + r) * K + k0 + c8;
        float4 x = *(const float4*)pa;
        float4 y = *(const float4*)(pa + 4);
        f16x8 o;
        o[0] = (_Float16)x.x; o[1] = (_Float16)x.y; o[2] = (_Float16)x.z; o[3] = (_Float16)x.w;
        o[4] = (_Float16)y.x; o[5] = (_Float16)y.y; o[6] = (_Float16)y.z; o[7] = (_Float16)y.w;
        *(f16x8*)(sA + r * 64 + (c8 ^ ((r & 7) << 3))) = o;
      }
    }
    __syncthreads();
#pragma unroll
    for (int kk = 0; kk < 64; kk += 32) {
      f16x8 af[4];
#pragma unroll
      for (int mf = 0; mf < 4; ++mf) {
        int row = wm * 64 + mf * 16 + lrow;
        af[mf] = *(const f16x8*)(sA + row * 64 + ((kk + lk) ^ ((row & 7) << 3)));
      }
#pragma unroll
      for (int nf = 0; nf < 4; ++nf) {
        int row = wn * 64 + nf * 16 + lrow;
        f16x8 bf = *(const f16x8*)(sB + row * 64 + ((kk + lk) ^ ((row & 7) << 3)));
#pragma unroll
        for (int mf = 0; mf < 4; ++mf)
          acc[mf][nf] = __builtin_amdgcn_mfma_f32_16x16x32_f16(af[mf], bf, acc[mf][nf], 0, 0, 0);
      }
    }
    __syncthreads();
  }

  if (OUTMODE == 0) {
    _Float16* C = (_Float16*)Cv;
    int b = m0 >> 11;
    int ml = (m0 & 2047) + wm * 64 + (lane >> 4) * 4;
#pragma unroll
    for (int nf = 0; nf < 4; ++nf) {
      int n = n0 + wn * 64 + nf * 16 + lrow;
      _Float16* row = C + ((size_t)(b * ND + n)) * NL + ml;
#pragma unroll
      for (int mf = 0; mf < 4; ++mf) {
        f16x4 v;
        v[0] = (_Float16)acc[mf][nf][0];
        v[1] = (_Float16)acc[mf][nf][1];
        v[2] = (_Float16)acc[mf][nf][2];
        v[3] = (_Float16)acc[mf][nf][3];
        *(f16x4*)(row + mf * 16) = v;
      }
    }
  } else {
    float* C = (float*)Cv;
#pragma unroll
    for (int mf = 0; mf < 4; ++mf)
#pragma unroll
      for (int nf = 0; nf < 4; ++nf) {
        int row = m0 + wm * 64 + mf * 16 + (lane >> 4) * 4;
        int col = n0 + wn * 64 + nf * 16 + lrow;
#pragma unroll
        for (int r = 0; r < 4; ++r)
          C[(size_t)(row + r) * ND + col] = acc[mf][nf][r];
      }
  }
}

// =================== FFT correlation + top-7 + softmax (register Stockham) ===================
__device__ __forceinline__ int SW(int i) { return i ^ ((i >> 4) & 7); }

__device__ __forceinline__ float2 cadd2(float2 a, float2 b) { return make_float2(a.x + b.x, a.y + b.y); }
__device__ __forceinline__ float2 csub2(float2 a, float2 b) { return make_float2(a.x - b.x, a.y - b.y); }
__device__ __forceinline__ float2 cmul2(float2 a, float2 b) {
  return make_float2(a.x * b.x - a.y * b.y, a.x * b.y + a.y * b.x);
}
__device__ __forceinline__ float2 cjs2(float2 a, float s) { return make_float2(-s * a.y, s * a.x); }

__device__ __forceinline__ void dft4(float2& b0, float2& b1, float2& b2, float2& b3, float s) {
  float2 t0 = cadd2(b0, b2), t1 = csub2(b0, b2);
  float2 t2 = cadd2(b1, b3), t3 = cjs2(csub2(b1, b3), s);
  b0 = cadd2(t0, t2);
  b1 = cadd2(t1, t3);
  b2 = csub2(t0, t2);
  b3 = csub2(t1, t3);
}

__device__ __forceinline__ void dft8(float2 a[8], float s) {
  float2 e0 = a[0], e1 = a[2], e2 = a[4], e3 = a[6];
  float2 o0 = a[1], o1 = a[3], o2 = a[5], o3 = a[7];
  dft4(e0, e1, e2, e3, s);
  dft4(o0, o1, o2, o3, s);
  const float c = 0.70710678118654752f;
  float2 w1 = make_float2(c, s * c);
  float2 w3 = make_float2(-c, s * c);
  o1 = cmul2(o1, w1);
  o2 = cjs2(o2, s);
  o3 = cmul2(o3, w3);
  a[0] = cadd2(e0, o0);
  a[4] = csub2(e0, o0);
  a[1] = cadd2(e1, o1);
  a[5] = csub2(e1, o1);
  a[2] = cadd2(e2, o2);
  a[6] = csub2(e2, o2);
  a[3] = cadd2(e3, o3);
  a[7] = csub2(e3, o3);
}

template <int LS>
__device__ __forceinline__ void pass8(const float2* __restrict__ in, float2* __restrict__ out,
                                      float s, int t) {
  int k = t & (LS - 1);
  int blk = t / LS;
  float2 a[8];
#pragma unroll
  for (int r = 0; r < 8; ++r) a[r] = in[SW(t + 256 * r)];
  if (LS > 1) {
    float ang = s * (6.283185307179586f / (float)(LS * 8)) * (float)k;
    float2 w;
    sincosf(ang, &w.y, &w.x);
    float2 wr = w;
    a[1] = cmul2(a[1], wr);
#pragma unroll
    for (int r = 2; r < 8; ++r) {
      wr = cmul2(wr, w);
      a[r] = cmul2(a[r], wr);
    }
  }
  dft8(a, s);
  int ob = blk * (LS * 8) + k;
#pragma unroll
  for (int r = 0; r < 8; ++r) out[SW(ob + LS * r)] = a[r];
}

__global__ __launch_bounds__(256) void fft_topk_kernel(
    const float* __restrict__ Qt, const float* __restrict__ Kt,
    float* __restrict__ topw, int* __restrict__ topi) {
  __shared__ float2 X[2048];
  __shared__ float2 Y[2048];
  __shared__ float cv[4];
  __shared__ int ct[4];

  int t = threadIdx.x;
  size_t rix = blockIdx.x;
  const float* q = Qt + rix * NL;
  const float* k = Kt + rix * NL;

#pragma unroll
  for (int it = 0; it < 2; ++it) {
    int i0 = 4 * t + 1024 * it;
    float4 vq = *(const float4*)(q + i0);
    float4 vk = *(const float4*)(k + i0);
    X[SW(i0 + 0)] = make_float2(vq.x, vk.x);
    X[SW(i0 + 1)] = make_float2(vq.y, vk.y);
    X[SW(i0 + 2)] = make_float2(vq.z, vk.z);
    X[SW(i0 + 3)] = make_float2(vq.w, vk.w);
  }
  __syncthreads();

  pass8<1>(X, Y, -1.0f, t);
  __syncthreads();
  pass8<8>(Y, X, -1.0f, t);
  __syncthreads();
  pass8<64>(X, Y, -1.0f, t);
  __syncthreads();
#pragma unroll
  for (int h = 0; h < 2; ++h) {
    int b = t + 256 * h;
    float2 a[4];
#pragma unroll
    for (int r = 0; r < 4; ++r) a[r] = Y[SW(b + 512 * r)];
    float ang = -(6.283185307179586f / 2048.0f) * (float)b;
    float2 w;
    sincosf(ang, &w.y, &w.x);
    a[1] = cmul2(a[1], w);
    float2 w2 = cmul2(w, w);
    a[2] = cmul2(a[2], w2);
    a[3] = cmul2(a[3], cmul2(w2, w));
    dft4(a[0], a[1], a[2], a[3], -1.0f);
#pragma unroll
    for (int r = 0; r < 4; ++r) X[SW(b + 512 * r)] = a[r];
  }
  __syncthreads();

#pragma unroll
  for (int it = 0; it < 8; ++it) {
    int f = t + 256 * it;
    int nf = (2048 - f) & 2047;
    float2 zf = X[SW(f)];
    float2 zn = X[SW(nf)];
    float a = zf.x, b2 = zf.y, c = zn.x, d = zn.y;
    float p = 0.5f * (a + c), qq = 0.5f * (b2 - d);
    float r2 = 0.5f * (b2 + d), s2 = -0.5f * (a - c);
    Y[SW(f)] = make_float2((p * r2 + qq * s2) * (1.0f / 2048.0f),
                           (qq * r2 - p * s2) * (1.0f / 2048.0f));
  }
  __syncthreads();

  pass8<1>(Y, X, 1.0f, t);
  __syncthreads();
  pass8<8>(X, Y, 1.0f, t);
  __syncthreads();
  pass8<64>(Y, X, 1.0f, t);
  __syncthreads();

  float lv[8];
  int lt[8];
#pragma unroll
  for (int h = 0; h < 2; ++h) {
    int b = t + 256 * h;
    float2 a[4];
#pragma unroll
    for (int r = 0; r < 4; ++r) a[r] = X[SW(b + 512 * r)];
    float ang = (6.283185307179586f / 2048.0f) * (float)b;
    float2 w;
    sincosf(ang, &w.y, &w.x);
    a[1] = cmul2(a[1], w);
    float2 w2 = cmul2(w, w);
    a[2] = cmul2(a[2], w2);
    a[3] = cmul2(a[3], cmul2(w2, w));
    dft4(a[0], a[1], a[2], a[3], 1.0f);
#pragma unroll
    for (int r = 0; r < 4; ++r) {
      lv[h * 4 + r] = a[r].x;
      lt[h * 4 + r] = b + 512 * r;
    }
  }

  int lane = t & 63, wave = t >> 6;
  float sel_v[KTOP];
  int sel_t[KTOP];
#pragma unroll
  for (int pass = 0; pass < KTOP; ++pass) {
    float bv = -3.0e38f;
    int bt = 0x7FFFFFFF;
#pragma unroll
    for (int j = 0; j < 8; ++j)
      if (lv[j] > bv || (lv[j] == bv && lt[j] < bt)) { bv = lv[j]; bt = lt[j]; }
#pragma unroll
    for (int m = 1; m < 64; m <<= 1) {
      float ov = __shfl_xor(bv, m, 64);
      int ot = __shfl_xor(bt, m, 64);
      if (ov > bv || (ov == bv && ot < bt)) { bv = ov; bt = ot; }
    }
    if (lane == 0) { cv[wave] = bv; ct[wave] = bt; }
    __syncthreads();
    float fv = cv[0];
    int ft = ct[0];
#pragma unroll
    for (int w = 1; w < 4; ++w) {
      float ov = cv[w];
      int ot = ct[w];
      if (ov > fv || (ov == fv && ot < ft)) { fv = ov; ft = ot; }
    }
    sel_v[pass] = fv;
    sel_t[pass] = ft;
#pragma unroll
    for (int j = 0; j < 8; ++j)
      if (lt[j] == ft) lv[j] = -3.0e38f;
    __syncthreads();
  }

  if (t == 0) {
    float m = sel_v[0], ssum = 0.f, w[KTOP];
#pragma unroll
    for (int i = 0; i < KTOP; ++i) { w[i] = expf(sel_v[i] - m); ssum += w[i]; }
#pragma unroll
    for (int i = 0; i < KTOP; ++i) {
      topw[rix * KTOP + i] = w[i] / ssum;
      topi[rix * KTOP + i] = sel_t[i];
    }
  }
}

// ---------------- roll (mod-64 over Dh) + weight + scramble write (f16, swizzled out) -------
__global__ __launch_bounds__(256) void roll_kernel(
    const _Float16* __restrict__ V, const float* __restrict__ topw,
    const int* __restrict__ topi, _Float16* __restrict__ out) {
  __shared__ float vt[64][68];
  __shared__ float ws[64][8];
  __shared__ int ts[64][8];
  int blk = blockIdx.x;
  int b = blk >> 9;
  int h = (blk >> 5) & 15;
  int lc = blk & 31;
  int t = threadIdx.x;

#pragma unroll
  for (int it = 0; it < 2; ++it) {
    int e = it * 256 + t;
    int d = e >> 3, c8 = (e & 7) << 3;
    f16x8 v = *(const f16x8*)(V + ((size_t)(b * ND + h * 64 + d)) * NL + lc * 64 + c8);
#pragma unroll
    for (int j = 0; j < 8; ++j) vt[d][c8 + j] = (float)v[j];
  }
  for (int e = t; e < 64 * KTOP; e += 256) {
    int d = e / KTOP, i = e % KTOP;
    size_t rix = ((size_t)(b * 16 + h)) * 64 + d;
    ws[d][i] = topw[rix * KTOP + i];
    ts[d][i] = topi[rix * KTOP + i] & 63;
  }
  __syncthreads();

  int hi = lc >> 4;
  int c0 = (lc & 15) * 64;
#pragma unroll
  for (int it = 0; it < 16; ++it) {
    int e = it * 256 + t;
    int d = e >> 6, r = e & 63;
    float s = 0.f;
#pragma unroll
    for (int i = 0; i < KTOP; ++i) s += ws[d][i] * vt[(d - ts[d][i]) & 63][r];
    int rowp = d * 32 + h * 2 + hi;
    int col = c0 + r;
    // swizzled f16 store (matches gll-consumer layout: k ^ ((m&7)<<3))
    out[((size_t)(b * NL + rowp)) * ND + (col ^ ((rowp & 7) << 3))] = (_Float16)s;
  }
}

// ------------------------------------- launcher ---------------------------------------------
extern "C" void kernel_launch(void* const* d_in, const int* in_sizes, int n_in,
                              void* d_out, int out_size, void* d_ws, size_t ws_size,
                              hipStream_t stream) {
  (void)in_sizes; (void)n_in; (void)out_size; (void)ws_size;
  const float* queries = (const float*)d_in[0];
  const float* keys    = (const float*)d_in[1];
  const float* values  = (const float*)d_in[2];
  const float* wq = (const float*)d_in[3];
  const float* wk = (const float*)d_in[4];
  const float* wv = (const float*)d_in[5];
  const float* wo = (const float*)d_in[6];
  float* outp = (float*)d_out;

  const size_t MB = 1024 * 1024;
  char* ws = (char*)d_ws;
  short*    wsplit = (short*)ws;                  // wq/wk bf16 hi+lo: 8MB
  _Float16* wf16   = (_Float16*)(ws + 8 * MB);    // wv,wo f16: 4MB
  float*    Qt     = (float*)(ws + 12 * MB);      // (8,1024,2048) f32 = 64MB; later Vp (f16)
  float*    Kt     = (float*)(ws + 76 * MB);      // 64MB; later Xs (f16)
  float*    topw   = (float*)(ws + 140 * MB);
  int*      topi   = (int*)(ws + 140 * MB + (size_t)8192 * KTOP * 4);

  short* wqh = wsplit + (size_t)0 * ND * ND;
  short* wql = wsplit + (size_t)1 * ND * ND;
  short* wkh = wsplit + (size_t)2 * ND * ND;
  short* wkl = wsplit + (size_t)3 * ND * ND;
  _Float16* wv16 = wf16 + (size_t)0 * ND * ND;
  _Float16* wo16 = wf16 + (size_t)1 * ND * ND;

  _Float16* Vp = (_Float16*)Qt;  // reuse after fft
  _Float16* Xs = (_Float16*)Kt;  // reuse after fft

  wprep_kernel<<<dim3(1024, 4), 256, 0, stream>>>(wq, wk, wv, wo, wsplit, wf16);

  gemm_split<<<1024, 256, 0, stream>>>(queries, wqh, wql, Qt);
  gemm_split<<<1024, 256, 0, stream>>>(keys, wkh, wkl, Kt);

  fft_topk_kernel<<<8192, 256, 0, stream>>>(Qt, Kt, topw, topi);

  gemm_f16<0, true><<<1024, 256, 0, stream>>>(values, wv16, Vp);

  roll_kernel<<<NB * NH * 32, 256, 0, stream>>>(Vp, topw, topi, Xs);

  gemm_f16<2, false><<<1024, 256, 0, stream>>>(Xs, wo16, outp);
}

// Round 7
// 493.615 us; speedup vs baseline: 2.7413x; 1.1041x over previous
//
#include <hip/hip_runtime.h>
#include <math.h>

#define NB 8
#define NL 2048
#define ND 1024
#define NH 16
#define KTOP 7

typedef __attribute__((ext_vector_type(4))) float f32x4;
typedef __attribute__((ext_vector_type(8))) short s16x8;
typedef __attribute__((ext_vector_type(8))) _Float16 f16x8;
typedef __attribute__((ext_vector_type(4))) _Float16 f16x4;

__device__ __forceinline__ unsigned short f2bf(float x) {
  unsigned u = __float_as_uint(x);
  u = (u + 0x7FFFu + ((u >> 16) & 1u)) >> 16;
  return (unsigned short)u;
}
__device__ __forceinline__ float bf2f(unsigned short h) {
  return __uint_as_float(((unsigned)h) << 16);
}
__device__ __forceinline__ unsigned cvtpk_bf16(float a, float b) {
  unsigned d;
  asm("v_cvt_pk_bf16_f32 %0, %1, %2" : "=v"(d) : "v"(a), "v"(b));
  return d;  // [15:0]=bf16(a), [31:16]=bf16(b), RNE
}
__device__ __forceinline__ float lo16(unsigned h) { return __uint_as_float(h << 16); }
__device__ __forceinline__ float hi16(unsigned h) { return __uint_as_float(h & 0xffff0000u); }

__device__ __forceinline__ void gll16(const void* g, void* l) {
  __builtin_amdgcn_global_load_lds(
      (const __attribute__((address_space(1))) void*)g,
      (__attribute__((address_space(3))) void*)l, 16, 0, 0);
}

// ---------------- weight prep ----------------
// y=0,1 (wq,wk): transpose -> split bf16 hi/lo, swizzled for BK=32 tiles (k ^ ((n&3)<<3))
// y=2,3 (wv,wo): transpose -> f16, swizzled for BK=64 tiles (k ^ ((n&7)<<3))
__global__ __launch_bounds__(256) void wprep_kernel(
    const float* __restrict__ w0, const float* __restrict__ w1,
    const float* __restrict__ w2, const float* __restrict__ w3,
    short* __restrict__ wsplit, _Float16* __restrict__ wf16) {
  __shared__ float tile[32][33];
  int y = blockIdx.y;
  const float* in = (y == 0) ? w0 : (y == 1) ? w1 : (y == 2) ? w2 : w3;
  int bx = blockIdx.x & 31, by = blockIdx.x >> 5;
  int tx = threadIdx.x & 31, ty = threadIdx.x >> 5;
#pragma unroll
  for (int i = 0; i < 4; ++i)
    tile[ty + i * 8][tx] = in[(size_t)(by * 32 + ty + i * 8) * ND + bx * 32 + tx];
  __syncthreads();
#pragma unroll
  for (int i = 0; i < 4; ++i) {
    float x = tile[tx][ty + i * 8];
    int n = bx * 32 + ty + i * 8;
    int k = by * 32 + tx;
    if (y < 2) {
      short* oh = wsplit + (size_t)(2 * y) * ND * ND;
      short* ol = wsplit + (size_t)(2 * y + 1) * ND * ND;
      unsigned short h = f2bf(x);
      unsigned short l = f2bf(x - bf2f(h));
      size_t o = (size_t)n * ND + (k ^ ((n & 3) << 3));
      oh[o] = (short)h;
      ol[o] = (short)l;
    } else {
      _Float16* of = wf16 + (size_t)(y - 2) * ND * ND;
      of[(size_t)n * ND + (k ^ ((n & 7) << 3))] = (_Float16)x;
    }
  }
}

// ---------------- split-bf16 GEMM: C^T = (A f32 x BT split-bf16), out (B,1024,2048) f32 -----
__global__ __launch_bounds__(256) void gemm_split(
    const float* __restrict__ A, const short* __restrict__ BhT,
    const short* __restrict__ BlT, float* __restrict__ Ct) {
  constexpr int K = 1024;
  __shared__ short ah[4096], al[4096], bh[4096], bl[4096];  // 32KB, BK=32
  int t = threadIdx.x;
  int wg = (blockIdx.x & 7) * 128 + (blockIdx.x >> 3);  // bijective XCD swizzle
  int m0 = (wg >> 3) << 7, n0 = (wg & 7) << 7;
  int lane = t & 63;
  int wm = (t >> 7) & 1, wn = (t >> 6) & 1;
  int lrow = lane & 15, lk8 = (lane >> 4) << 3;

  f32x4 acc[4][4] = {};

  for (int k0 = 0; k0 < K; k0 += 32) {
    // B hi/lo: async direct-to-LDS (source pre-split + pre-swizzled)
#pragma unroll
    for (int it = 0; it < 2; ++it) {
      int cb = it * 256 + t;
      int r = cb >> 2, c8 = (cb & 3) << 3;
      int lo = it * 2048 + (t & 192) * 8;  // wave-uniform (halfs)
      gll16(BhT + (size_t)(n0 + r) * K + k0 + c8, bh + lo);
      gll16(BlT + (size_t)(n0 + r) * K + k0 + c8, bl + lo);
    }
    // A: load f32, packed cvt split to bf16 hi/lo, swizzled LDS write
#pragma unroll
    for (int it = 0; it < 2; ++it) {
      int ca = it * 256 + t;
      int r = ca >> 2, c8 = (ca & 3) << 3;
      const float* pa = A + (size_t)(m0 + r) * K + k0 + c8;
      float4 x = *(const float4*)pa;
      float4 y = *(const float4*)(pa + 4);
      unsigned h0 = cvtpk_bf16(x.x, x.y);
      unsigned h1 = cvtpk_bf16(x.z, x.w);
      unsigned h2 = cvtpk_bf16(y.x, y.y);
      unsigned h3 = cvtpk_bf16(y.z, y.w);
      float r0 = x.x - lo16(h0), r1 = x.y - hi16(h0);
      float r2 = x.z - lo16(h1), r3 = x.w - hi16(h1);
      float r4 = y.x - lo16(h2), r5 = y.y - hi16(h2);
      float r6 = y.z - lo16(h3), r7 = y.w - hi16(h3);
      unsigned l0 = cvtpk_bf16(r0, r1);
      unsigned l1 = cvtpk_bf16(r2, r3);
      unsigned l2 = cvtpk_bf16(r4, r5);
      unsigned l3 = cvtpk_bf16(r6, r7);
      int wi = r * 32 + (c8 ^ ((r & 3) << 3));
      *(uint4*)(ah + wi) = make_uint4(h0, h1, h2, h3);
      *(uint4*)(al + wi) = make_uint4(l0, l1, l2, l3);
    }
    __syncthreads();

    s16x8 afh[4], afl[4];
#pragma unroll
    for (int mf = 0; mf < 4; ++mf) {
      int row = wm * 64 + mf * 16 + lrow;
      int idx = row * 32 + (lk8 ^ ((row & 3) << 3));
      afh[mf] = *(const s16x8*)(ah + idx);
      afl[mf] = *(const s16x8*)(al + idx);
    }
#pragma unroll
    for (int nf = 0; nf < 4; ++nf) {
      int row = wn * 64 + nf * 16 + lrow;
      int idx = row * 32 + (lk8 ^ ((row & 3) << 3));
      s16x8 bfh = *(const s16x8*)(bh + idx);
      s16x8 bfl = *(const s16x8*)(bl + idx);
      // term-middle ordering: same-acc dependency distance = 4 MFMAs
#pragma unroll
      for (int mf = 0; mf < 4; ++mf)
        acc[mf][nf] = __builtin_amdgcn_mfma_f32_16x16x32_bf16(afh[mf], bfh, acc[mf][nf], 0, 0, 0);
#pragma unroll
      for (int mf = 0; mf < 4; ++mf)
        acc[mf][nf] = __builtin_amdgcn_mfma_f32_16x16x32_bf16(afh[mf], bfl, acc[mf][nf], 0, 0, 0);
#pragma unroll
      for (int mf = 0; mf < 4; ++mf)
        acc[mf][nf] = __builtin_amdgcn_mfma_f32_16x16x32_bf16(afl[mf], bfh, acc[mf][nf], 0, 0, 0);
    }
    __syncthreads();
  }

  // epilogue: C^T (B,1024,2048) f32, float4 stores along m
  int b = m0 >> 11;
  int mlbase = (m0 & 2047) + wm * 64 + (lane >> 4) * 4;
#pragma unroll
  for (int nf = 0; nf < 4; ++nf) {
    int n = n0 + wn * 64 + nf * 16 + lrow;
    float* rowp = Ct + ((size_t)(b * ND + n)) * NL + mlbase;
#pragma unroll
    for (int mf = 0; mf < 4; ++mf)
      *(float4*)(rowp + mf * 16) = *(float4*)&acc[mf][nf];
  }
}

// ---------------- f16 GEMM: A x BT(f16 pre-swizzled, gll) --------------------------------
template <int OUTMODE, bool AF32>
__global__ __launch_bounds__(256) void gemm_f16(
    const void* __restrict__ Av, const _Float16* __restrict__ BT,
    void* __restrict__ Cv) {
  constexpr int K = 1024;
  __shared__ _Float16 sA[8192];  // 128 x 64, swizzled
  __shared__ _Float16 sB[8192];
  int t = threadIdx.x;
  int wg = (blockIdx.x & 7) * 128 + (blockIdx.x >> 3);
  int m0 = (wg >> 3) << 7, n0 = (wg & 7) << 7;
  int lane = t & 63;
  int wm = (t >> 7) & 1, wn = (t >> 6) & 1;
  int lrow = lane & 15, lk = (lane >> 4) << 3;

  f32x4 acc[4][4] = {};

  for (int k0 = 0; k0 < K; k0 += 64) {
#pragma unroll
    for (int it = 0; it < 4; ++it) {
      int e = it * 256 + t;
      int r = e >> 3, c8 = (e & 7) << 3;
      int lo = it * 2048 + (t & 192) * 8;
      gll16(BT + (size_t)(n0 + r) * K + k0 + c8, sB + lo);
      if (!AF32) {
        const _Float16* Af = (const _Float16*)Av;
        gll16(Af + (size_t)(m0 + r) * K + k0 + c8, sA + lo);
      }
    }
    if (AF32) {
      const float* Af = (const float*)Av;
#pragma unroll
      for (int it = 0; it < 4; ++it) {
        int ca = it * 256 + t;
        int r = ca >> 3, c8 = (ca & 7) << 3;
        const float* pa = Af + (size_t)(m0 + r) * K + k0 + c8;
        float4 x = *(const float4*)pa;
        float4 y = *(const float4*)(pa + 4);
        f16x8 o;
        o[0] = (_Float16)x.x; o[1] = (_Float16)x.y; o[2] = (_Float16)x.z; o[3] = (_Float16)x.w;
        o[4] = (_Float16)y.x; o[5] = (_Float16)y.y; o[6] = (_Float16)y.z; o[7] = (_Float16)y.w;
        *(f16x8*)(sA + r * 64 + (c8 ^ ((r & 7) << 3))) = o;
      }
    }
    __syncthreads();
#pragma unroll
    for (int kk = 0; kk < 64; kk += 32) {
      f16x8 af[4];
#pragma unroll
      for (int mf = 0; mf < 4; ++mf) {
        int row = wm * 64 + mf * 16 + lrow;
        af[mf] = *(const f16x8*)(sA + row * 64 + ((kk + lk) ^ ((row & 7) << 3)));
      }
#pragma unroll
      for (int nf = 0; nf < 4; ++nf) {
        int row = wn * 64 + nf * 16 + lrow;
        f16x8 bf = *(const f16x8*)(sB + row * 64 + ((kk + lk) ^ ((row & 7) << 3)));
#pragma unroll
        for (int mf = 0; mf < 4; ++mf)
          acc[mf][nf] = __builtin_amdgcn_mfma_f32_16x16x32_f16(af[mf], bf, acc[mf][nf], 0, 0, 0);
      }
    }
    __syncthreads();
  }

  if (OUTMODE == 0) {
    _Float16* C = (_Float16*)Cv;
    int b = m0 >> 11;
    int ml = (m0 & 2047) + wm * 64 + (lane >> 4) * 4;
#pragma unroll
    for (int nf = 0; nf < 4; ++nf) {
      int n = n0 + wn * 64 + nf * 16 + lrow;
      _Float16* row = C + ((size_t)(b * ND + n)) * NL + ml;
#pragma unroll
      for (int mf = 0; mf < 4; ++mf) {
        f16x4 v;
        v[0] = (_Float16)acc[mf][nf][0];
        v[1] = (_Float16)acc[mf][nf][1];
        v[2] = (_Float16)acc[mf][nf][2];
        v[3] = (_Float16)acc[mf][nf][3];
        *(f16x4*)(row + mf * 16) = v;
      }
    }
  } else {
    float* C = (float*)Cv;
#pragma unroll
    for (int mf = 0; mf < 4; ++mf)
#pragma unroll
      for (int nf = 0; nf < 4; ++nf) {
        int row = m0 + wm * 64 + mf * 16 + (lane >> 4) * 4;
        int col = n0 + wn * 64 + nf * 16 + lrow;
#pragma unroll
        for (int r = 0; r < 4; ++r)
          C[(size_t)(row + r) * ND + col] = acc[mf][nf][r];
      }
  }
}

// =================== FFT correlation + top-7 + softmax (register Stockham) ===================
__device__ __forceinline__ int SW(int i) { return i ^ ((i >> 4) & 7); }

__device__ __forceinline__ float2 cadd2(float2 a, float2 b) { return make_float2(a.x + b.x, a.y + b.y); }
__device__ __forceinline__ float2 csub2(float2 a, float2 b) { return make_float2(a.x - b.x, a.y - b.y); }
__device__ __forceinline__ float2 cmul2(float2 a, float2 b) {
  return make_float2(a.x * b.x - a.y * b.y, a.x * b.y + a.y * b.x);
}
__device__ __forceinline__ float2 cjs2(float2 a, float s) { return make_float2(-s * a.y, s * a.x); }
// e^{i*2*pi*rev} via HW trig (input in revolutions, |rev| < 1)
__device__ __forceinline__ float2 wtw(float rev) {
  return make_float2(__builtin_amdgcn_cosf(rev), __builtin_amdgcn_sinf(rev));
}

__device__ __forceinline__ void dft4(float2& b0, float2& b1, float2& b2, float2& b3, float s) {
  float2 t0 = cadd2(b0, b2), t1 = csub2(b0, b2);
  float2 t2 = cadd2(b1, b3), t3 = cjs2(csub2(b1, b3), s);
  b0 = cadd2(t0, t2);
  b1 = cadd2(t1, t3);
  b2 = csub2(t0, t2);
  b3 = csub2(t1, t3);
}

__device__ __forceinline__ void dft8(float2 a[8], float s) {
  float2 e0 = a[0], e1 = a[2], e2 = a[4], e3 = a[6];
  float2 o0 = a[1], o1 = a[3], o2 = a[5], o3 = a[7];
  dft4(e0, e1, e2, e3, s);
  dft4(o0, o1, o2, o3, s);
  const float c = 0.70710678118654752f;
  float2 w1 = make_float2(c, s * c);
  float2 w3 = make_float2(-c, s * c);
  o1 = cmul2(o1, w1);
  o2 = cjs2(o2, s);
  o3 = cmul2(o3, w3);
  a[0] = cadd2(e0, o0);
  a[4] = csub2(e0, o0);
  a[1] = cadd2(e1, o1);
  a[5] = csub2(e1, o1);
  a[2] = cadd2(e2, o2);
  a[6] = csub2(e2, o2);
  a[3] = cadd2(e3, o3);
  a[7] = csub2(e3, o3);
}

template <int LS>
__device__ __forceinline__ void pass8(const float2* __restrict__ in, float2* __restrict__ out,
                                      float s, int t) {
  float2 a[8];
  const float2* ip = in + (t ^ ((t >> 4) & 7));  // SW(t+256r) = SW(t)+256r (256r in bits>=8)
#pragma unroll
  for (int r = 0; r < 8; ++r) a[r] = ip[256 * r];
  int k = t & (LS - 1);
  if (LS > 1) {
    float kf = s * (1.0f / (LS * 8)) * (float)k;
    float2 w1 = wtw(kf);
    float2 w4 = wtw(4.0f * kf);
    float2 w2 = cmul2(w1, w1);
    float2 w3 = cmul2(w2, w1);
    float2 w5 = cmul2(w4, w1);
    float2 w6 = cmul2(w4, w2);
    float2 w7 = cmul2(w4, w3);
    a[1] = cmul2(a[1], w1);
    a[2] = cmul2(a[2], w2);
    a[3] = cmul2(a[3], w3);
    a[4] = cmul2(a[4], w4);
    a[5] = cmul2(a[5], w5);
    a[6] = cmul2(a[6], w6);
    a[7] = cmul2(a[7], w7);
  }
  dft8(a, s);
  int ob = (t / LS) * (LS * 8) + k;
#pragma unroll
  for (int r = 0; r < 8; ++r) out[SW(ob + LS * r)] = a[r];
}

__global__ __launch_bounds__(256) void fft_topk_kernel(
    const float* __restrict__ Qt, const float* __restrict__ Kt,
    float* __restrict__ topw, int* __restrict__ topi) {
  __shared__ float2 X[2048];
  __shared__ float2 Y[2048];
  __shared__ float cv[2][4];
  __shared__ int ct[2][4];

  int t = threadIdx.x;
  size_t rix = blockIdx.x;
  const float* q = Qt + rix * NL;
  const float* k = Kt + rix * NL;

  // load packed z = Q + i*K. NOTE: SW(i0+j) = SW(i0) ^ j for j<4 (XOR, not add —
  // round-6 bug: pointer+j carried into the swizzle bits and corrupted LDS).
#pragma unroll
  for (int it = 0; it < 2; ++it) {
    int i0 = 4 * t + 1024 * it;
    float4 vq = *(const float4*)(q + i0);
    float4 vk = *(const float4*)(k + i0);
    int swb = SW(i0);
    X[swb ^ 0] = make_float2(vq.x, vk.x);
    X[swb ^ 1] = make_float2(vq.y, vk.y);
    X[swb ^ 2] = make_float2(vq.z, vk.z);
    X[swb ^ 3] = make_float2(vq.w, vk.w);
  }
  __syncthreads();

  pass8<1>(X, Y, -1.0f, t);
  __syncthreads();
  pass8<8>(Y, X, -1.0f, t);
  __syncthreads();
  pass8<64>(X, Y, -1.0f, t);
  __syncthreads();
#pragma unroll
  for (int h = 0; h < 2; ++h) {
    int b = t + 256 * h;
    float2 a[4];
    const float2* yp = Y + SW(b);  // SW(b+512r)=SW(b)+512r (512r in bits>=9)
#pragma unroll
    for (int r = 0; r < 4; ++r) a[r] = yp[512 * r];
    float2 w = wtw(-(1.0f / 2048.0f) * (float)b);
    float2 w2 = cmul2(w, w);
    a[1] = cmul2(a[1], w);
    a[2] = cmul2(a[2], w2);
    a[3] = cmul2(a[3], cmul2(w2, w));
    dft4(a[0], a[1], a[2], a[3], -1.0f);
    float2* xp = X + SW(b);
#pragma unroll
    for (int r = 0; r < 4; ++r) xp[512 * r] = a[r];
  }
  __syncthreads();

  // spectrum untangle: S = FQ * conj(FK), scaled by 1/2048; X -> Y
#pragma unroll
  for (int it = 0; it < 8; ++it) {
    int f = t + 256 * it;
    int nf = (2048 - f) & 2047;
    float2 zf = X[SW(t) + 256 * it];
    float2 zn = X[SW(nf)];
    float a = zf.x, b2 = zf.y, c = zn.x, d = zn.y;
    float p = 0.5f * (a + c), qq = 0.5f * (b2 - d);
    float r2 = 0.5f * (b2 + d), s2 = -0.5f * (a - c);
    Y[SW(t) + 256 * it] = make_float2((p * r2 + qq * s2) * (1.0f / 2048.0f),
                                      (qq * r2 - p * s2) * (1.0f / 2048.0f));
  }
  __syncthreads();

  pass8<1>(Y, X, 1.0f, t);
  __syncthreads();
  pass8<8>(X, Y, 1.0f, t);
  __syncthreads();
  pass8<64>(Y, X, 1.0f, t);
  __syncthreads();

  float lv[8];
  int lt[8];
#pragma unroll
  for (int h = 0; h < 2; ++h) {
    int b = t + 256 * h;
    float2 a[4];
    const float2* xp = X + SW(b);
#pragma unroll
    for (int r = 0; r < 4; ++r) a[r] = xp[512 * r];
    float2 w = wtw((1.0f / 2048.0f) * (float)b);
    float2 w2 = cmul2(w, w);
    a[1] = cmul2(a[1], w);
    a[2] = cmul2(a[2], w2);
    a[3] = cmul2(a[3], cmul2(w2, w));
    dft4(a[0], a[1], a[2], a[3], 1.0f);
#pragma unroll
    for (int r = 0; r < 4; ++r) {
      lv[h * 4 + r] = a[r].x;
      lt[h * 4 + r] = b + 512 * r;
    }
  }

  // top-7: cached per-thread best, owner-only rescan, 1 barrier/pass
  int lane = t & 63, wave = t >> 6;
  float bv = lv[0];
  int bt = lt[0];
#pragma unroll
  for (int j = 1; j < 8; ++j)
    if (lv[j] > bv) { bv = lv[j]; bt = lt[j]; }

  float sel_v[KTOP];
  int sel_t[KTOP];
#pragma unroll
  for (int pass = 0; pass < KTOP; ++pass) {
    float rv = bv;
    int rt = bt;
#pragma unroll
    for (int m = 1; m < 64; m <<= 1) {
      float ov = __shfl_xor(rv, m, 64);
      int ot = __shfl_xor(rt, m, 64);
      if (ov > rv) { rv = ov; rt = ot; }
    }
    if (lane == 0) { cv[pass & 1][wave] = rv; ct[pass & 1][wave] = rt; }
    __syncthreads();
    float fv = cv[pass & 1][0];
    int ft = ct[pass & 1][0];
#pragma unroll
    for (int w = 1; w < 4; ++w) {
      float ov = cv[pass & 1][w];
      if (ov > fv) { fv = ov; ft = ct[pass & 1][w]; }
    }
    sel_v[pass] = fv;
    sel_t[pass] = ft;
    if (bt == ft) {  // owner lane only: invalidate + rescan (other waves skip via execz)
#pragma unroll
      for (int j = 0; j < 8; ++j)
        if (lt[j] == ft) lv[j] = -3.0e38f;
      bv = lv[0];
      bt = lt[0];
#pragma unroll
      for (int j = 1; j < 8; ++j)
        if (lv[j] > bv) { bv = lv[j]; bt = lt[j]; }
    }
  }

  if (t == 0) {
    float m = sel_v[0], ssum = 0.f, w[KTOP];
#pragma unroll
    for (int i = 0; i < KTOP; ++i) { w[i] = expf(sel_v[i] - m); ssum += w[i]; }
#pragma unroll
    for (int i = 0; i < KTOP; ++i) {
      topw[rix * KTOP + i] = w[i] / ssum;
      topi[rix * KTOP + i] = sel_t[i];
    }
  }
}

// ---------------- roll (mod-64 over Dh) + weight + scramble write (f16, swizzled out) -------
__global__ __launch_bounds__(256) void roll_kernel(
    const _Float16* __restrict__ V, const float* __restrict__ topw,
    const int* __restrict__ topi, _Float16* __restrict__ out) {
  __shared__ float vt[64][68];
  __shared__ float ws[64][8];
  __shared__ int ts[64][8];
  int blk = blockIdx.x;
  int b = blk >> 9;
  int h = (blk >> 5) & 15;
  int lc = blk & 31;
  int t = threadIdx.x;

#pragma unroll
  for (int it = 0; it < 2; ++it) {
    int e = it * 256 + t;
    int d = e >> 3, c8 = (e & 7) << 3;
    f16x8 v = *(const f16x8*)(V + ((size_t)(b * ND + h * 64 + d)) * NL + lc * 64 + c8);
#pragma unroll
    for (int j = 0; j < 8; ++j) vt[d][c8 + j] = (float)v[j];
  }
  for (int e = t; e < 64 * KTOP; e += 256) {
    int d = e / KTOP, i = e % KTOP;
    size_t rix = ((size_t)(b * 16 + h)) * 64 + d;
    ws[d][i] = topw[rix * KTOP + i];
    ts[d][i] = topi[rix * KTOP + i] & 63;
  }
  __syncthreads();

  int hi = lc >> 4;
  int c0 = (lc & 15) * 64;
#pragma unroll
  for (int it = 0; it < 16; ++it) {
    int e = it * 256 + t;
    int d = e >> 6, r = e & 63;
    float s = 0.f;
#pragma unroll
    for (int i = 0; i < KTOP; ++i) s += ws[d][i] * vt[(d - ts[d][i]) & 63][r];
    int rowp = d * 32 + h * 2 + hi;
    int col = c0 + r;
    out[((size_t)(b * NL + rowp)) * ND + (col ^ ((rowp & 7) << 3))] = (_Float16)s;
  }
}

// ------------------------------------- launcher ---------------------------------------------
extern "C" void kernel_launch(void* const* d_in, const int* in_sizes, int n_in,
                              void* d_out, int out_size, void* d_ws, size_t ws_size,
                              hipStream_t stream) {
  (void)in_sizes; (void)n_in; (void)out_size; (void)ws_size;
  const float* queries = (const float*)d_in[0];
  const float* keys    = (const float*)d_in[1];
  const float* values  = (const float*)d_in[2];
  const float* wq = (const float*)d_in[3];
  const float* wk = (const float*)d_in[4];
  const float* wv = (const float*)d_in[5];
  const float* wo = (const float*)d_in[6];
  float* outp = (float*)d_out;

  const size_t MB = 1024 * 1024;
  char* ws = (char*)d_ws;
  short*    wsplit = (short*)ws;                  // wq/wk bf16 hi+lo: 8MB
  _Float16* wf16   = (_Float16*)(ws + 8 * MB);    // wv,wo f16: 4MB
  float*    Qt     = (float*)(ws + 12 * MB);      // (8,1024,2048) f32 = 64MB; later Vp (f16)
  float*    Kt     = (float*)(ws + 76 * MB);      // 64MB; later Xs (f16)
  float*    topw   = (float*)(ws + 140 * MB);
  int*      topi   = (int*)(ws + 140 * MB + (size_t)8192 * KTOP * 4);

  short* wqh = wsplit + (size_t)0 * ND * ND;
  short* wql = wsplit + (size_t)1 * ND * ND;
  short* wkh = wsplit + (size_t)2 * ND * ND;
  short* wkl = wsplit + (size_t)3 * ND * ND;
  _Float16* wv16 = wf16 + (size_t)0 * ND * ND;
  _Float16* wo16 = wf16 + (size_t)1 * ND * ND;

  _Float16* Vp = (_Float16*)Qt;  // reuse after fft
  _Float16* Xs = (_Float16*)Kt;  // reuse after fft

  wprep_kernel<<<dim3(1024, 4), 256, 0, stream>>>(wq, wk, wv, wo, wsplit, wf16);

  gemm_split<<<1024, 256, 0, stream>>>(queries, wqh, wql, Qt);
  gemm_split<<<1024, 256, 0, stream>>>(keys, wkh, wkl, Kt);

  fft_topk_kernel<<<8192, 256, 0, stream>>>(Qt, Kt, topw, topi);

  gemm_f16<0, true><<<1024, 256, 0, stream>>>(values, wv16, Vp);

  roll_kernel<<<NB * NH * 32, 256, 0, stream>>>(Vp, topw, topi, Xs);

  gemm_f16<2, false><<<1024, 256, 0, stream>>>(Xs, wo16, outp);
}

// Round 8
// 467.076 us; speedup vs baseline: 2.8970x; 1.0568x over previous
//
#include <hip/hip_runtime.h>
#include <math.h>

#define NB 8
#define NL 2048
#define ND 1024
#define NH 16
#define KTOP 7

typedef __attribute__((ext_vector_type(4))) float f32x4;
typedef __attribute__((ext_vector_type(8))) short s16x8;
typedef __attribute__((ext_vector_type(8))) _Float16 f16x8;
typedef __attribute__((ext_vector_type(4))) _Float16 f16x4;

__device__ __forceinline__ unsigned short f2bf(float x) {
  unsigned u = __float_as_uint(x);
  u = (u + 0x7FFFu + ((u >> 16) & 1u)) >> 16;
  return (unsigned short)u;
}
__device__ __forceinline__ float bf2f(unsigned short h) {
  return __uint_as_float(((unsigned)h) << 16);
}
__device__ __forceinline__ unsigned cvtpk_bf16(float a, float b) {
  unsigned d;
  asm("v_cvt_pk_bf16_f32 %0, %1, %2" : "=v"(d) : "v"(a), "v"(b));
  return d;  // [15:0]=bf16(a), [31:16]=bf16(b), RNE
}
__device__ __forceinline__ float lo16(unsigned h) { return __uint_as_float(h << 16); }
__device__ __forceinline__ float hi16(unsigned h) { return __uint_as_float(h & 0xffff0000u); }

__device__ __forceinline__ void gll16(const void* g, void* l) {
  __builtin_amdgcn_global_load_lds(
      (const __attribute__((address_space(1))) void*)g,
      (__attribute__((address_space(3))) void*)l, 16, 0, 0);
}

// split f32x8 -> bf16 hi/lo uint4 pair, store to LDS
__device__ __forceinline__ void asplit_write(float4 x, float4 y, short* ah, short* al, int wi) {
  unsigned h0 = cvtpk_bf16(x.x, x.y);
  unsigned h1 = cvtpk_bf16(x.z, x.w);
  unsigned h2 = cvtpk_bf16(y.x, y.y);
  unsigned h3 = cvtpk_bf16(y.z, y.w);
  float r0 = x.x - lo16(h0), r1 = x.y - hi16(h0);
  float r2 = x.z - lo16(h1), r3 = x.w - hi16(h1);
  float r4 = y.x - lo16(h2), r5 = y.y - hi16(h2);
  float r6 = y.z - lo16(h3), r7 = y.w - hi16(h3);
  unsigned l0 = cvtpk_bf16(r0, r1);
  unsigned l1 = cvtpk_bf16(r2, r3);
  unsigned l2 = cvtpk_bf16(r4, r5);
  unsigned l3 = cvtpk_bf16(r6, r7);
  *(uint4*)(ah + wi) = make_uint4(h0, h1, h2, h3);
  *(uint4*)(al + wi) = make_uint4(l0, l1, l2, l3);
}

// ---------------- weight prep ----------------
// y=0,1 (wq,wk): transpose -> split bf16 hi/lo, swizzled for BK=32 (k ^ (((n>>1)&3)<<3))
// y=2,3 (wv,wo): transpose -> f16, swizzled for BK=64 tiles (k ^ ((n&7)<<3))
__global__ __launch_bounds__(256) void wprep_kernel(
    const float* __restrict__ w0, const float* __restrict__ w1,
    const float* __restrict__ w2, const float* __restrict__ w3,
    short* __restrict__ wsplit, _Float16* __restrict__ wf16) {
  __shared__ float tile[32][33];
  int y = blockIdx.y;
  const float* in = (y == 0) ? w0 : (y == 1) ? w1 : (y == 2) ? w2 : w3;
  int bx = blockIdx.x & 31, by = blockIdx.x >> 5;
  int tx = threadIdx.x & 31, ty = threadIdx.x >> 5;
#pragma unroll
  for (int i = 0; i < 4; ++i)
    tile[ty + i * 8][tx] = in[(size_t)(by * 32 + ty + i * 8) * ND + bx * 32 + tx];
  __syncthreads();
#pragma unroll
  for (int i = 0; i < 4; ++i) {
    float x = tile[tx][ty + i * 8];
    int n = bx * 32 + ty + i * 8;
    int k = by * 32 + tx;
    if (y < 2) {
      short* oh = wsplit + (size_t)(2 * y) * ND * ND;
      short* ol = wsplit + (size_t)(2 * y + 1) * ND * ND;
      unsigned short h = f2bf(x);
      unsigned short l = f2bf(x - bf2f(h));
      size_t o = (size_t)n * ND + (k ^ (((n >> 1) & 3) << 3));
      oh[o] = (short)h;
      ol[o] = (short)l;
    } else {
      _Float16* of = wf16 + (size_t)(y - 2) * ND * ND;
      of[(size_t)n * ND + (k ^ ((n & 7) << 3))] = (_Float16)x;
    }
  }
}

// ---------------- split-bf16 GEMM: C^T = (A f32 x BT split-bf16), out (B,1024,2048) f32 -----
// Double-buffered BK=32: issue-early staging (A global->reg, B gll->LDS), write-late A split.
__global__ __launch_bounds__(256) void gemm_split(
    const float* __restrict__ A, const short* __restrict__ BhT,
    const short* __restrict__ BlT, float* __restrict__ Ct) {
  constexpr int K = 1024;
  // 64KB: buf b at b*16384 shorts; within buf: ah 0, al 4096, bh 8192, bl 12288
  __shared__ short smem[32768];
  int t = threadIdx.x;
  int wg = (blockIdx.x & 7) * 128 + (blockIdx.x >> 3);  // bijective XCD swizzle
  int m0 = (wg >> 3) << 7, n0 = (wg & 7) << 7;
  int lane = t & 63;
  int wm = (t >> 7) & 1, wn = (t >> 6) & 1;
  int lrow = lane & 15, lk8 = (lane >> 4) << 3;

  // staging geometry (per thread): rows r0 (it=0) and r1=r0+64 (it=1), k-chunk c8
  int r0 = t >> 2, r1 = r0 + 64;
  int c8 = (t & 3) << 3;
  int wi0 = r0 * 32 + (c8 ^ (((r0 >> 1) & 3) << 3));
  int wi1 = r1 * 32 + (c8 ^ (((r1 >> 1) & 3) << 3));
  int lo0 = (t & 192) * 8;         // wave-uniform LDS offset (shorts), it=0
  int lo1 = 2048 + (t & 192) * 8;  // it=1

  const float* pa0 = A + (size_t)(m0 + r0) * K + c8;
  const float* pa1 = A + (size_t)(m0 + r1) * K + c8;
  const short* pb0h = BhT + (size_t)(n0 + r0) * K + c8;
  const short* pb1h = BhT + (size_t)(n0 + r1) * K + c8;
  const short* pb0l = BlT + (size_t)(n0 + r0) * K + c8;
  const short* pb1l = BlT + (size_t)(n0 + r1) * K + c8;

  // loop-invariant fragment read offsets (shorts within a buffer)
  int iA[4], iB[4];
#pragma unroll
  for (int f = 0; f < 4; ++f) {
    int ra = wm * 64 + f * 16 + lrow;
    iA[f] = ra * 32 + (lk8 ^ (((ra >> 1) & 3) << 3));
    int rb = wn * 64 + f * 16 + lrow;
    iB[f] = rb * 32 + (lk8 ^ (((rb >> 1) & 3) << 3));
  }

  f32x4 acc[4][4] = {};

  // ---- prologue: stage k0=0 into buf0 ----
  float4 sx0 = *(const float4*)(pa0);
  float4 sy0 = *(const float4*)(pa0 + 4);
  float4 sx1 = *(const float4*)(pa1);
  float4 sy1 = *(const float4*)(pa1 + 4);
  gll16(pb0h, smem + 8192 + lo0);
  gll16(pb1h, smem + 8192 + lo1);
  gll16(pb0l, smem + 12288 + lo0);
  gll16(pb1l, smem + 12288 + lo1);
  asplit_write(sx0, sy0, smem, smem + 4096, wi0);
  asplit_write(sx1, sy1, smem, smem + 4096, wi1);
  __syncthreads();

  for (int k0 = 0; k0 < K; k0 += 32) {
    short* cb = smem + ((k0 >> 5) & 1) * 16384;
    short* nb = smem + ((((k0 >> 5) & 1) ^ 1) * 16384);
    bool more = (k0 + 32) < K;
    if (more) {
      // issue-early: next A tile -> regs, next B tile -> LDS (async)
      sx0 = *(const float4*)(pa0 + k0 + 32);
      sy0 = *(const float4*)(pa0 + k0 + 36);
      sx1 = *(const float4*)(pa1 + k0 + 32);
      sy1 = *(const float4*)(pa1 + k0 + 36);
      gll16(pb0h + k0 + 32, nb + 8192 + lo0);
      gll16(pb1h + k0 + 32, nb + 8192 + lo1);
      gll16(pb0l + k0 + 32, nb + 12288 + lo0);
      gll16(pb1l + k0 + 32, nb + 12288 + lo1);
    }
    // ---- compute from cb ----
    s16x8 afh[4], afl[4];
#pragma unroll
    for (int mf = 0; mf < 4; ++mf) {
      afh[mf] = *(const s16x8*)(cb + iA[mf]);
      afl[mf] = *(const s16x8*)(cb + 4096 + iA[mf]);
    }
#pragma unroll
    for (int nf = 0; nf < 4; ++nf) {
      s16x8 bfh = *(const s16x8*)(cb + 8192 + iB[nf]);
      s16x8 bfl = *(const s16x8*)(cb + 12288 + iB[nf]);
      // term-grouped: same-acc dependency distance = 4 MFMAs
#pragma unroll
      for (int mf = 0; mf < 4; ++mf)
        acc[mf][nf] = __builtin_amdgcn_mfma_f32_16x16x32_bf16(afh[mf], bfh, acc[mf][nf], 0, 0, 0);
#pragma unroll
      for (int mf = 0; mf < 4; ++mf)
        acc[mf][nf] = __builtin_amdgcn_mfma_f32_16x16x32_bf16(afh[mf], bfl, acc[mf][nf], 0, 0, 0);
#pragma unroll
      for (int mf = 0; mf < 4; ++mf)
        acc[mf][nf] = __builtin_amdgcn_mfma_f32_16x16x32_bf16(afl[mf], bfh, acc[mf][nf], 0, 0, 0);
    }
    if (more) {
      // write-late: split A into nb (compiler waits only the A loads, gll stays in flight)
      asplit_write(sx0, sy0, nb, nb + 4096, wi0);
      asplit_write(sx1, sy1, nb, nb + 4096, wi1);
    }
    __syncthreads();
  }

  // epilogue: C^T (B,1024,2048) f32, float4 stores along m
  int b = m0 >> 11;
  int mlbase = (m0 & 2047) + wm * 64 + (lane >> 4) * 4;
#pragma unroll
  for (int nf = 0; nf < 4; ++nf) {
    int n = n0 + wn * 64 + nf * 16 + lrow;
    float* rowp = Ct + ((size_t)(b * ND + n)) * NL + mlbase;
#pragma unroll
    for (int mf = 0; mf < 4; ++mf)
      *(float4*)(rowp + mf * 16) = *(float4*)&acc[mf][nf];
  }
}

// ---------------- f16 GEMM: A x BT(f16 pre-swizzled, gll) --------------------------------
template <int OUTMODE, bool AF32>
__global__ __launch_bounds__(256) void gemm_f16(
    const void* __restrict__ Av, const _Float16* __restrict__ BT,
    void* __restrict__ Cv) {
  constexpr int K = 1024;
  __shared__ _Float16 sA[8192];  // 128 x 64, swizzled
  __shared__ _Float16 sB[8192];
  int t = threadIdx.x;
  int wg = (blockIdx.x & 7) * 128 + (blockIdx.x >> 3);
  int m0 = (wg >> 3) << 7, n0 = (wg & 7) << 7;
  int lane = t & 63;
  int wm = (t >> 7) & 1, wn = (t >> 6) & 1;
  int lrow = lane & 15, lk = (lane >> 4) << 3;

  f32x4 acc[4][4] = {};

  for (int k0 = 0; k0 < K; k0 += 64) {
#pragma unroll
    for (int it = 0; it < 4; ++it) {
      int e = it * 256 + t;
      int r = e >> 3, c8 = (e & 7) << 3;
      int lo = it * 2048 + (t & 192) * 8;
      gll16(BT + (size_t)(n0 + r) * K + k0 + c8, sB + lo);
      if (!AF32) {
        const _Float16* Af = (const _Float16*)Av;
        gll16(Af + (size_t)(m0 + r) * K + k0 + c8, sA + lo);
      }
    }
    if (AF32) {
      const float* Af = (const float*)Av;
#pragma unroll
      for (int it = 0; it < 4; ++it) {
        int ca = it * 256 + t;
        int r = ca >> 3, c8 = (ca & 7) << 3;
        const float* pa = Af + (size_t)(m0 + r) * K + k0 + c8;
        float4 x = *(const float4*)pa;
        float4 y = *(const float4*)(pa + 4);
        f16x8 o;
        o[0] = (_Float16)x.x; o[1] = (_Float16)x.y; o[2] = (_Float16)x.z; o[3] = (_Float16)x.w;
        o[4] = (_Float16)y.x; o[5] = (_Float16)y.y; o[6] = (_Float16)y.z; o[7] = (_Float16)y.w;
        *(f16x8*)(sA + r * 64 + (c8 ^ ((r & 7) << 3))) = o;
      }
    }
    __syncthreads();
#pragma unroll
    for (int kk = 0; kk < 64; kk += 32) {
      f16x8 af[4];
#pragma unroll
      for (int mf = 0; mf < 4; ++mf) {
        int row = wm * 64 + mf * 16 + lrow;
        af[mf] = *(const f16x8*)(sA + row * 64 + ((kk + lk) ^ ((row & 7) << 3)));
      }
#pragma unroll
      for (int nf = 0; nf < 4; ++nf) {
        int row = wn * 64 + nf * 16 + lrow;
        f16x8 bf = *(const f16x8*)(sB + row * 64 + ((kk + lk) ^ ((row & 7) << 3)));
#pragma unroll
        for (int mf = 0; mf < 4; ++mf)
          acc[mf][nf] = __builtin_amdgcn_mfma_f32_16x16x32_f16(af[mf], bf, acc[mf][nf], 0, 0, 0);
      }
    }
    __syncthreads();
  }

  if (OUTMODE == 0) {
    _Float16* C = (_Float16*)Cv;
    int b = m0 >> 11;
    int ml = (m0 & 2047) + wm * 64 + (lane >> 4) * 4;
#pragma unroll
    for (int nf = 0; nf < 4; ++nf) {
      int n = n0 + wn * 64 + nf * 16 + lrow;
      _Float16* row = C + ((size_t)(b * ND + n)) * NL + ml;
#pragma unroll
      for (int mf = 0; mf < 4; ++mf) {
        f16x4 v;
        v[0] = (_Float16)acc[mf][nf][0];
        v[1] = (_Float16)acc[mf][nf][1];
        v[2] = (_Float16)acc[mf][nf][2];
        v[3] = (_Float16)acc[mf][nf][3];
        *(f16x4*)(row + mf * 16) = v;
      }
    }
  } else {
    float* C = (float*)Cv;
#pragma unroll
    for (int mf = 0; mf < 4; ++mf)
#pragma unroll
      for (int nf = 0; nf < 4; ++nf) {
        int row = m0 + wm * 64 + mf * 16 + (lane >> 4) * 4;
        int col = n0 + wn * 64 + nf * 16 + lrow;
#pragma unroll
        for (int r = 0; r < 4; ++r)
          C[(size_t)(row + r) * ND + col] = acc[mf][nf][r];
      }
  }
}

// =================== FFT correlation + top-7 + softmax (register Stockham) ===================
__device__ __forceinline__ int SW(int i) { return i ^ ((i >> 4) & 7); }

__device__ __forceinline__ float2 cadd2(float2 a, float2 b) { return make_float2(a.x + b.x, a.y + b.y); }
__device__ __forceinline__ float2 csub2(float2 a, float2 b) { return make_float2(a.x - b.x, a.y - b.y); }
__device__ __forceinline__ float2 cmul2(float2 a, float2 b) {
  return make_float2(a.x * b.x - a.y * b.y, a.x * b.y + a.y * b.x);
}
__device__ __forceinline__ float2 cjs2(float2 a, float s) { return make_float2(-s * a.y, s * a.x); }
// e^{i*2*pi*rev} via HW trig (input in revolutions, |rev| < 1)
__device__ __forceinline__ float2 wtw(float rev) {
  return make_float2(__builtin_amdgcn_cosf(rev), __builtin_amdgcn_sinf(rev));
}

__device__ __forceinline__ void dft4(float2& b0, float2& b1, float2& b2, float2& b3, float s) {
  float2 t0 = cadd2(b0, b2), t1 = csub2(b0, b2);
  float2 t2 = cadd2(b1, b3), t3 = cjs2(csub2(b1, b3), s);
  b0 = cadd2(t0, t2);
  b1 = cadd2(t1, t3);
  b2 = csub2(t0, t2);
  b3 = csub2(t1, t3);
}

__device__ __forceinline__ void dft8(float2 a[8], float s) {
  float2 e0 = a[0], e1 = a[2], e2 = a[4], e3 = a[6];
  float2 o0 = a[1], o1 = a[3], o2 = a[5], o3 = a[7];
  dft4(e0, e1, e2, e3, s);
  dft4(o0, o1, o2, o3, s);
  const float c = 0.70710678118654752f;
  float2 w1 = make_float2(c, s * c);
  float2 w3 = make_float2(-c, s * c);
  o1 = cmul2(o1, w1);
  o2 = cjs2(o2, s);
  o3 = cmul2(o3, w3);
  a[0] = cadd2(e0, o0);
  a[4] = csub2(e0, o0);
  a[1] = cadd2(e1, o1);
  a[5] = csub2(e1, o1);
  a[2] = cadd2(e2, o2);
  a[6] = csub2(e2, o2);
  a[3] = cadd2(e3, o3);
  a[7] = csub2(e3, o3);
}

template <int LS>
__device__ __forceinline__ void pass8(const float2* __restrict__ in, float2* __restrict__ out,
                                      float s, int t) {
  float2 a[8];
  const float2* ip = in + (t ^ ((t >> 4) & 7));  // SW(t+256r) = SW(t)+256r (256r in bits>=8)
#pragma unroll
  for (int r = 0; r < 8; ++r) a[r] = ip[256 * r];
  int k = t & (LS - 1);
  if (LS > 1) {
    float kf = s * (1.0f / (LS * 8)) * (float)k;
    float2 w1 = wtw(kf);
    float2 w4 = wtw(4.0f * kf);
    float2 w2 = cmul2(w1, w1);
    float2 w3 = cmul2(w2, w1);
    float2 w5 = cmul2(w4, w1);
    float2 w6 = cmul2(w4, w2);
    float2 w7 = cmul2(w4, w3);
    a[1] = cmul2(a[1], w1);
    a[2] = cmul2(a[2], w2);
    a[3] = cmul2(a[3], w3);
    a[4] = cmul2(a[4], w4);
    a[5] = cmul2(a[5], w5);
    a[6] = cmul2(a[6], w6);
    a[7] = cmul2(a[7], w7);
  }
  dft8(a, s);
  int ob = (t / LS) * (LS * 8) + k;
#pragma unroll
  for (int r = 0; r < 8; ++r) out[SW(ob + LS * r)] = a[r];
}

__global__ __launch_bounds__(256) void fft_topk_kernel(
    const float* __restrict__ Qt, const float* __restrict__ Kt,
    float* __restrict__ topw, int* __restrict__ topi) {
  __shared__ float2 X[2048];
  __shared__ float2 Y[2048];
  __shared__ float cv[2][4];
  __shared__ int ct[2][4];

  int t = threadIdx.x;
  size_t rix = blockIdx.x;
  const float* q = Qt + rix * NL;
  const float* k = Kt + rix * NL;

  // load packed z = Q + i*K. SW(i0+j) = SW(i0) ^ j for j<4 (XOR, not add!)
#pragma unroll
  for (int it = 0; it < 2; ++it) {
    int i0 = 4 * t + 1024 * it;
    float4 vq = *(const float4*)(q + i0);
    float4 vk = *(const float4*)(k + i0);
    int swb = SW(i0);
    X[swb ^ 0] = make_float2(vq.x, vk.x);
    X[swb ^ 1] = make_float2(vq.y, vk.y);
    X[swb ^ 2] = make_float2(vq.z, vk.z);
    X[swb ^ 3] = make_float2(vq.w, vk.w);
  }
  __syncthreads();

  pass8<1>(X, Y, -1.0f, t);
  __syncthreads();
  pass8<8>(Y, X, -1.0f, t);
  __syncthreads();
  pass8<64>(X, Y, -1.0f, t);
  __syncthreads();
#pragma unroll
  for (int h = 0; h < 2; ++h) {
    int b = t + 256 * h;
    float2 a[4];
    const float2* yp = Y + SW(b);  // SW(b+512r)=SW(b)+512r (512r in bits>=9)
#pragma unroll
    for (int r = 0; r < 4; ++r) a[r] = yp[512 * r];
    float2 w = wtw(-(1.0f / 2048.0f) * (float)b);
    float2 w2 = cmul2(w, w);
    a[1] = cmul2(a[1], w);
    a[2] = cmul2(a[2], w2);
    a[3] = cmul2(a[3], cmul2(w2, w));
    dft4(a[0], a[1], a[2], a[3], -1.0f);
    float2* xp = X + SW(b);
#pragma unroll
    for (int r = 0; r < 4; ++r) xp[512 * r] = a[r];
  }
  __syncthreads();

  // spectrum untangle: S = FQ * conj(FK), scaled by 1/2048; X -> Y
#pragma unroll
  for (int it = 0; it < 8; ++it) {
    int f = t + 256 * it;
    int nf = (2048 - f) & 2047;
    float2 zf = X[SW(t) + 256 * it];
    float2 zn = X[SW(nf)];
    float a = zf.x, b2 = zf.y, c = zn.x, d = zn.y;
    float p = 0.5f * (a + c), qq = 0.5f * (b2 - d);
    float r2 = 0.5f * (b2 + d), s2 = -0.5f * (a - c);
    Y[SW(t) + 256 * it] = make_float2((p * r2 + qq * s2) * (1.0f / 2048.0f),
                                      (qq * r2 - p * s2) * (1.0f / 2048.0f));
  }
  __syncthreads();

  pass8<1>(Y, X, 1.0f, t);
  __syncthreads();
  pass8<8>(X, Y, 1.0f, t);
  __syncthreads();
  pass8<64>(Y, X, 1.0f, t);
  __syncthreads();

  float lv[8];
  int lt[8];
#pragma unroll
  for (int h = 0; h < 2; ++h) {
    int b = t + 256 * h;
    float2 a[4];
    const float2* xp = X + SW(b);
#pragma unroll
    for (int r = 0; r < 4; ++r) a[r] = xp[512 * r];
    float2 w = wtw((1.0f / 2048.0f) * (float)b);
    float2 w2 = cmul2(w, w);
    a[1] = cmul2(a[1], w);
    a[2] = cmul2(a[2], w2);
    a[3] = cmul2(a[3], cmul2(w2, w));
    dft4(a[0], a[1], a[2], a[3], 1.0f);
#pragma unroll
    for (int r = 0; r < 4; ++r) {
      lv[h * 4 + r] = a[r].x;
      lt[h * 4 + r] = b + 512 * r;
    }
  }

  // top-7: cached per-thread best, owner-only rescan, 1 barrier/pass
  int lane = t & 63, wave = t >> 6;
  float bv = lv[0];
  int bt = lt[0];
#pragma unroll
  for (int j = 1; j < 8; ++j)
    if (lv[j] > bv) { bv = lv[j]; bt = lt[j]; }

  float sel_v[KTOP];
  int sel_t[KTOP];
#pragma unroll
  for (int pass = 0; pass < KTOP; ++pass) {
    float rv = bv;
    int rt = bt;
#pragma unroll
    for (int m = 1; m < 64; m <<= 1) {
      float ov = __shfl_xor(rv, m, 64);
      int ot = __shfl_xor(rt, m, 64);
      if (ov > rv) { rv = ov; rt = ot; }
    }
    if (lane == 0) { cv[pass & 1][wave] = rv; ct[pass & 1][wave] = rt; }
    __syncthreads();
    float fv = cv[pass & 1][0];
    int ft = ct[pass & 1][0];
#pragma unroll
    for (int w = 1; w < 4; ++w) {
      float ov = cv[pass & 1][w];
      if (ov > fv) { fv = ov; ft = ct[pass & 1][w]; }
    }
    sel_v[pass] = fv;
    sel_t[pass] = ft;
    if (bt == ft) {  // owner lane only: invalidate + rescan (other waves skip via execz)
#pragma unroll
      for (int j = 0; j < 8; ++j)
        if (lt[j] == ft) lv[j] = -3.0e38f;
      bv = lv[0];
      bt = lt[0];
#pragma unroll
      for (int j = 1; j < 8; ++j)
        if (lv[j] > bv) { bv = lv[j]; bt = lt[j]; }
    }
  }

  if (t == 0) {
    float m = sel_v[0], ssum = 0.f, w[KTOP];
#pragma unroll
    for (int i = 0; i < KTOP; ++i) { w[i] = expf(sel_v[i] - m); ssum += w[i]; }
#pragma unroll
    for (int i = 0; i < KTOP; ++i) {
      topw[rix * KTOP + i] = w[i] / ssum;
      topi[rix * KTOP + i] = sel_t[i];
    }
  }
}

// ---------------- roll (mod-64 over Dh) + weight + scramble write (f16, swizzled out) -------
__global__ __launch_bounds__(256) void roll_kernel(
    const _Float16* __restrict__ V, const float* __restrict__ topw,
    const int* __restrict__ topi, _Float16* __restrict__ out) {
  __shared__ float vt[64][68];
  __shared__ float ws[64][8];
  __shared__ int ts[64][8];
  int blk = blockIdx.x;
  int b = blk >> 9;
  int h = (blk >> 5) & 15;
  int lc = blk & 31;
  int t = threadIdx.x;

#pragma unroll
  for (int it = 0; it < 2; ++it) {
    int e = it * 256 + t;
    int d = e >> 3, c8 = (e & 7) << 3;
    f16x8 v = *(const f16x8*)(V + ((size_t)(b * ND + h * 64 + d)) * NL + lc * 64 + c8);
#pragma unroll
    for (int j = 0; j < 8; ++j) vt[d][c8 + j] = (float)v[j];
  }
  for (int e = t; e < 64 * KTOP; e += 256) {
    int d = e / KTOP, i = e % KTOP;
    size_t rix = ((size_t)(b * 16 + h)) * 64 + d;
    ws[d][i] = topw[rix * KTOP + i];
    ts[d][i] = topi[rix * KTOP + i] & 63;
  }
  __syncthreads();

  int hi = lc >> 4;
  int c0 = (lc & 15) * 64;
#pragma unroll
  for (int it = 0; it < 16; ++it) {
    int e = it * 256 + t;
    int d = e >> 6, r = e & 63;
    float s = 0.f;
#pragma unroll
    for (int i = 0; i < KTOP; ++i) s += ws[d][i] * vt[(d - ts[d][i]) & 63][r];
    int rowp = d * 32 + h * 2 + hi;
    int col = c0 + r;
    out[((size_t)(b * NL + rowp)) * ND + (col ^ ((rowp & 7) << 3))] = (_Float16)s;
  }
}

// ------------------------------------- launcher ---------------------------------------------
extern "C" void kernel_launch(void* const* d_in, const int* in_sizes, int n_in,
                              void* d_out, int out_size, void* d_ws, size_t ws_size,
                              hipStream_t stream) {
  (void)in_sizes; (void)n_in; (void)out_size; (void)ws_size;
  const float* queries = (const float*)d_in[0];
  const float* keys    = (const float*)d_in[1];
  const float* values  = (const float*)d_in[2];
  const float* wq = (const float*)d_in[3];
  const float* wk = (const float*)d_in[4];
  const float* wv = (const float*)d_in[5];
  const float* wo = (const float*)d_in[6];
  float* outp = (float*)d_out;

  const size_t MB = 1024 * 1024;
  char* ws = (char*)d_ws;
  short*    wsplit = (short*)ws;                  // wq/wk bf16 hi+lo: 8MB
  _Float16* wf16   = (_Float16*)(ws + 8 * MB);    // wv,wo f16: 4MB
  float*    Qt     = (float*)(ws + 12 * MB);      // (8,1024,2048) f32 = 64MB; later Vp (f16)
  float*    Kt     = (float*)(ws + 76 * MB);      // 64MB; later Xs (f16)
  float*    topw   = (float*)(ws + 140 * MB);
  int*      topi   = (int*)(ws + 140 * MB + (size_t)8192 * KTOP * 4);

  short* wqh = wsplit + (size_t)0 * ND * ND;
  short* wql = wsplit + (size_t)1 * ND * ND;
  short* wkh = wsplit + (size_t)2 * ND * ND;
  short* wkl = wsplit + (size_t)3 * ND * ND;
  _Float16* wv16 = wf16 + (size_t)0 * ND * ND;
  _Float16* wo16 = wf16 + (size_t)1 * ND * ND;

  _Float16* Vp = (_Float16*)Qt;  // reuse after fft
  _Float16* Xs = (_Float16*)Kt;  // reuse after fft

  wprep_kernel<<<dim3(1024, 4), 256, 0, stream>>>(wq, wk, wv, wo, wsplit, wf16);

  gemm_split<<<1024, 256, 0, stream>>>(queries, wqh, wql, Qt);
  gemm_split<<<1024, 256, 0, stream>>>(keys, wkh, wkl, Kt);

  fft_topk_kernel<<<8192, 256, 0, stream>>>(Qt, Kt, topw, topi);

  gemm_f16<0, true><<<1024, 256, 0, stream>>>(values, wv16, Vp);

  roll_kernel<<<NB * NH * 32, 256, 0, stream>>>(Vp, topw, topi, Xs);

  gemm_f16<2, false><<<1024, 256, 0, stream>>>(Xs, wo16, outp);
}